// Round 11
// baseline (468.192 us; speedup 1.0000x reference)
//
#include <hip/hip_runtime.h>

typedef unsigned short u16;
using bf16x8 = __attribute__((ext_vector_type(8))) __bf16;
using f32x4  = __attribute__((ext_vector_type(4))) float;
using s16x8  = __attribute__((ext_vector_type(8))) short;
using s16x4  = __attribute__((ext_vector_type(4))) short;

#define AS1 __attribute__((address_space(1)))
#define AS3 __attribute__((address_space(3)))

__device__ __forceinline__ void gload16(const u16* g, u16* l) {
  __builtin_amdgcn_global_load_lds((AS1 void*)(size_t)g, (AS3 void*)l, 16, 0, 0);
}

__device__ __forceinline__ u16 f2bf(float f) {
  unsigned u = __float_as_uint(f);
  u += 0x7fffu + ((u >> 16) & 1u);   // round-to-nearest-even
  return (u16)(u >> 16);
}
__device__ __forceinline__ float bf2f(u16 h) {
  return __uint_as_float(((unsigned)h) << 16);
}

// ---------------- elementwise f32 -> bf16 ----------------
__global__ __launch_bounds__(256) void cast_bf16_kernel(const float* __restrict__ x,
                                                        u16* __restrict__ y, int n) {
  int i = (blockIdx.x * 256 + threadIdx.x) * 4;
  if (i + 3 < n) {
    float4 v = *reinterpret_cast<const float4*>(x + i);
    s16x4 o;
    o[0] = (short)f2bf(v.x); o[1] = (short)f2bf(v.y);
    o[2] = (short)f2bf(v.z); o[3] = (short)f2bf(v.w);
    *reinterpret_cast<s16x4*>(y + i) = o;
  }
}

// ---------------- W [K][N] f32 -> WT [N][K] bf16 (64x64 tiles) ----------------
__global__ __launch_bounds__(256) void transpose_cast_kernel(const float* __restrict__ W,
                                                             u16* __restrict__ WT,
                                                             int K, int N) {
  __shared__ u16 tile[64][72];
  const int t = threadIdx.x;
  const int nb = blockIdx.x * 64, kb = blockIdx.y * 64;
  const int rr = t >> 3;        // 0..31
  const int cc = (t & 7) * 8;   // 0..56
#pragma unroll
  for (int pass = 0; pass < 2; ++pass) {
    const float* src = W + (size_t)(kb + pass * 32 + rr) * N + nb + cc;
    float4 a = *reinterpret_cast<const float4*>(src);
    float4 b = *reinterpret_cast<const float4*>(src + 4);
    u16* tr = &tile[pass * 32 + rr][cc];
    tr[0] = f2bf(a.x); tr[1] = f2bf(a.y); tr[2] = f2bf(a.z); tr[3] = f2bf(a.w);
    tr[4] = f2bf(b.x); tr[5] = f2bf(b.y); tr[6] = f2bf(b.z); tr[7] = f2bf(b.w);
  }
  __syncthreads();
#pragma unroll
  for (int pass = 0; pass < 2; ++pass) {
    s16x8 v;
#pragma unroll
    for (int j = 0; j < 8; ++j) v[j] = (short)tile[cc + j][pass * 32 + rr];
    *reinterpret_cast<s16x8*>(WT + (size_t)(nb + pass * 32 + rr) * K + kb + cc) = v;
  }
}

// ---------------- RMSNorm (bf16 in/out, f32 weight) ----------------
__global__ __launch_bounds__(256) void rmsnorm_kernel(const u16* __restrict__ x,
                                                      const float* __restrict__ w,
                                                      u16* __restrict__ y,
                                                      int R, int xs, int ys) {
  const int row = blockIdx.x, t = threadIdx.x;
  const u16* xr = x + (size_t)row * xs;
  float ss = 0.f;
  for (int i = t; i < R; i += 256) { float f = bf2f(xr[i]); ss += f * f; }
#pragma unroll
  for (int m = 32; m >= 1; m >>= 1) ss += __shfl_xor(ss, m);
  __shared__ float red[4];
  if ((t & 63) == 0) red[t >> 6] = ss;
  __syncthreads();
  float tot = red[0] + red[1] + red[2] + red[3];
  float r = rsqrtf(tot / (float)R + 1e-6f);
  u16* yr = y + (size_t)row * ys;
  for (int i = t; i < R; i += 256) yr[i] = f2bf(bf2f(xr[i]) * r * w[i]);
}

// ---------------- RoPE cos/sin table: [2048][32] each ----------------
__global__ __launch_bounds__(256) void rope_table_kernel(float* __restrict__ cost,
                                                         float* __restrict__ sint) {
  int idx = blockIdx.x * 256 + threadIdx.x;   // 65536
  int pos = idx >> 5, j = idx & 31;
  float inv = __expf(-(float)j * (9.210340371976184f / 32.0f));  // 10000^(-j/32)
  float f = (float)pos * inv;
  cost[idx] = cosf(f);
  sint[idx] = sinf(f);
}

// ---------------- qf build (vectorized): q [s][h*192] -> qf [h][s][192], RoPE + scale ----------------
__global__ __launch_bounds__(256) void build_qf_kernel(const u16* __restrict__ q,
                                                       const float* __restrict__ cost,
                                                       const float* __restrict__ sint,
                                                       u16* __restrict__ qf) {
  int tid = blockIdx.x * 256 + threadIdx.x;
  int o8 = tid * 8;
  if (o8 >= 32 * 2048 * 192) return;
  const float scale = 0.07216878364870323f;  // 192^-0.5 (folded into q)
  int c = (o8 % 192) >> 3;  // chunk 0..23
  int rest = o8 / 192;
  int s = rest & 2047, h = rest >> 11;
  const u16* qrow = q + ((size_t)s * 32 + h) * 192;
  s16x8 out;
  if (c < 16) {
    s16x8 v = *reinterpret_cast<const s16x8*>(qrow + c * 8);
#pragma unroll
    for (int j = 0; j < 8; ++j) out[j] = (short)f2bf(bf2f((u16)v[j]) * scale);
  } else {
    int j0 = c * 8 - 128;
    bool lo = j0 < 32;
    int jj0 = lo ? j0 : j0 - 32;
    s16x8 a = *reinterpret_cast<const s16x8*>(qrow + 128 + 2 * jj0);
    s16x8 b = *reinterpret_cast<const s16x8*>(qrow + 128 + 2 * jj0 + 8);
    float4 c0 = *reinterpret_cast<const float4*>(cost + s * 32 + jj0);
    float4 c1 = *reinterpret_cast<const float4*>(cost + s * 32 + jj0 + 4);
    float4 s0 = *reinterpret_cast<const float4*>(sint + s * 32 + jj0);
    float4 s1 = *reinterpret_cast<const float4*>(sint + s * 32 + jj0 + 4);
    float cs[8] = {c0.x, c0.y, c0.z, c0.w, c1.x, c1.y, c1.z, c1.w};
    float sn[8] = {s0.x, s0.y, s0.z, s0.w, s1.x, s1.y, s1.z, s1.w};
#pragma unroll
    for (int j = 0; j < 8; ++j) {
      float x0 = bf2f((u16)((j < 4) ? a[2 * j] : b[2 * j - 8]));
      float x1 = bf2f((u16)((j < 4) ? a[2 * j + 1] : b[2 * j - 7]));
      float v = lo ? (x0 * cs[j] - x1 * sn[j]) : (x1 * cs[j] + x0 * sn[j]);
      out[j] = (short)f2bf(v * scale);
    }
  }
  *reinterpret_cast<s16x8*>(qf + o8) = out;
}

// ---------------- kf build (vectorized): kv [s][h*256], ckv(stride 2112) -> kf [h][s][192] ----------------
__global__ __launch_bounds__(256) void build_kf_kernel(const u16* __restrict__ kv,
                                                       const u16* __restrict__ ckv,
                                                       const float* __restrict__ cost,
                                                       const float* __restrict__ sint,
                                                       u16* __restrict__ kf) {
  int tid = blockIdx.x * 256 + threadIdx.x;
  int o8 = tid * 8;
  if (o8 >= 32 * 2048 * 192) return;
  int c = (o8 % 192) >> 3;
  int rest = o8 / 192;
  int s = rest & 2047, h = rest >> 11;
  s16x8 out;
  if (c < 16) {
    out = *reinterpret_cast<const s16x8*>(kv + ((size_t)s * 32 + h) * 256 + c * 8);
  } else {
    int j0 = c * 8 - 128;
    bool lo = j0 < 32;
    int jj0 = lo ? j0 : j0 - 32;
    const u16* crow = ckv + (size_t)s * 2112 + 512;
    s16x8 a = *reinterpret_cast<const s16x8*>(crow + 2 * jj0);
    s16x8 b = *reinterpret_cast<const s16x8*>(crow + 2 * jj0 + 8);
    float4 c0 = *reinterpret_cast<const float4*>(cost + s * 32 + jj0);
    float4 c1 = *reinterpret_cast<const float4*>(cost + s * 32 + jj0 + 4);
    float4 s0 = *reinterpret_cast<const float4*>(sint + s * 32 + jj0);
    float4 s1 = *reinterpret_cast<const float4*>(sint + s * 32 + jj0 + 4);
    float cs[8] = {c0.x, c0.y, c0.z, c0.w, c1.x, c1.y, c1.z, c1.w};
    float sn[8] = {s0.x, s0.y, s0.z, s0.w, s1.x, s1.y, s1.z, s1.w};
#pragma unroll
    for (int j = 0; j < 8; ++j) {
      float x0 = bf2f((u16)((j < 4) ? a[2 * j] : b[2 * j - 8]));
      float x1 = bf2f((u16)((j < 4) ? a[2 * j + 1] : b[2 * j - 7]));
      float v = lo ? (x0 * cs[j] - x1 * sn[j]) : (x1 * cs[j] + x0 * sn[j]);
      out[j] = (short)f2bf(v);
    }
  }
  *reinterpret_cast<s16x8*>(kf + o8) = out;
}

// ---------------- vT build: kv [s][h*256+128+d] -> vT [h][128][2048] ----------------
__global__ __launch_bounds__(256) void vt_build_kernel(const u16* __restrict__ kv,
                                                       u16* __restrict__ vT) {
  __shared__ u16 tile[64][72];
  const int t = threadIdx.x;
  const int sb = blockIdx.x * 64, db = blockIdx.y * 64, h = blockIdx.z;
  const int rr = t >> 3, cc = (t & 7) * 8;
#pragma unroll
  for (int pass = 0; pass < 2; ++pass) {
    const u16* src = kv + (size_t)(sb + pass * 32 + rr) * 8192 + h * 256 + 128 + db + cc;
    s16x8 v = *reinterpret_cast<const s16x8*>(src);
#pragma unroll
    for (int j = 0; j < 8; ++j) tile[pass * 32 + rr][cc + j] = (u16)v[j];
  }
  __syncthreads();
#pragma unroll
  for (int pass = 0; pass < 2; ++pass) {
    s16x8 v;
#pragma unroll
    for (int j = 0; j < 8; ++j) v[j] = (short)tile[cc + j][pass * 32 + rr];
    *reinterpret_cast<s16x8*>(vT + ((size_t)h * 128 + db + pass * 32 + rr) * 2048 + sb + cc) = v;
  }
}

// ---------------- GEMM v3: C[M][N] = A[M][K](bf16) * BT[N][K](bf16)^T ----------------
// 128x128 tile, BK=32, 4 waves (2x2). 4-deep LDS pipeline, prefetch distance 3,
// one raw s_barrier/iter with counted vmcnt(8), XOR-swizzled LDS, setprio MFMA.
template <int OUT_BF16>
__global__ __launch_bounds__(256) void gemm_v3_kernel(const u16* __restrict__ A,
                                                      const u16* __restrict__ BT,
                                                      void* __restrict__ Cv,
                                                      int M, int N, int K) {
  __shared__ __align__(16) u16 S[4 * 8192];
  const int t0 = threadIdx.x;
  const int lane = t0 & 63, wave = t0 >> 6;
  const int wr = wave >> 1, wc = wave & 1;
  const int row0 = blockIdx.y * 128, col0 = blockIdx.x * 128;
  const int lrow = lane & 15, lkg = lane >> 4;

  const int lp = lane ^ ((lane >> 3) & 3);
  const int srow_off = lp >> 2;
  const int skel = (lp & 3) * 8;
  const int c0 = wave * 2, c1 = c0 + 1;
  const int arow_c0 = row0 + c0 * 16 + srow_off;
  const int arow_c1 = row0 + c1 * 16 + srow_off;
  int brow_c0 = col0 + c0 * 16 + srow_off; if (brow_c0 > N - 1) brow_c0 = N - 1;
  int brow_c1 = col0 + c1 * 16 + srow_off; if (brow_c1 > N - 1) brow_c1 = N - 1;

  int aoff[4], boff[4];
#pragma unroll
  for (int m = 0; m < 4; ++m) {
    int r = wr * 64 + m * 16 + lrow;
    int off = r * 32 + lkg * 8;
    aoff[m] = off ^ ((off >> 3) & 0x18);
    r = wc * 64 + m * 16 + lrow;
    off = r * 32 + lkg * 8;
    boff[m] = off ^ ((off >> 3) & 0x18);
  }

  const int NT = K >> 5;

#pragma unroll
  for (int pt = 0; pt < 3; ++pt) {
    u16* ab = &S[pt * 8192];
    const int kb = pt * 32 + skel;
    gload16(A  + (size_t)arow_c0 * K + kb, ab + c0 * 512);
    gload16(A  + (size_t)arow_c1 * K + kb, ab + c1 * 512);
    gload16(BT + (size_t)brow_c0 * K + kb, ab + 4096 + c0 * 512);
    gload16(BT + (size_t)brow_c1 * K + kb, ab + 4096 + c1 * 512);
  }

  f32x4 acc[4][4];
#pragma unroll
  for (int m = 0; m < 4; ++m)
#pragma unroll
    for (int n = 0; n < 4; ++n) acc[m][n] = 0.f;

  for (int t = 0; t < NT; ++t) {
    if (t + 2 < NT)      asm volatile("s_waitcnt vmcnt(8)" ::: "memory");
    else if (t + 1 < NT) asm volatile("s_waitcnt vmcnt(4)" ::: "memory");
    else                 asm volatile("s_waitcnt vmcnt(0)" ::: "memory");
    __builtin_amdgcn_s_barrier();
    __builtin_amdgcn_sched_barrier(0);

    const u16* ab = &S[(t & 3) * 8192];
    bf16x8 af[4], bb[4];
#pragma unroll
    for (int m = 0; m < 4; ++m)
      af[m] = *reinterpret_cast<const bf16x8*>(ab + aoff[m]);
#pragma unroll
    for (int n = 0; n < 4; ++n)
      bb[n] = *reinterpret_cast<const bf16x8*>(ab + 4096 + boff[n]);

    if (t + 3 < NT) {
      u16* sb = &S[((t + 3) & 3) * 8192];
      const int kb = (t + 3) * 32 + skel;
      gload16(A  + (size_t)arow_c0 * K + kb, sb + c0 * 512);
      gload16(A  + (size_t)arow_c1 * K + kb, sb + c1 * 512);
      gload16(BT + (size_t)brow_c0 * K + kb, sb + 4096 + c0 * 512);
      gload16(BT + (size_t)brow_c1 * K + kb, sb + 4096 + c1 * 512);
    }

    __builtin_amdgcn_s_setprio(1);
#pragma unroll
    for (int m = 0; m < 4; ++m)
#pragma unroll
      for (int n = 0; n < 4; ++n)
        acc[m][n] = __builtin_amdgcn_mfma_f32_16x16x32_bf16(af[m], bb[n], acc[m][n], 0, 0, 0);
    __builtin_amdgcn_s_setprio(0);
  }

#pragma unroll
  for (int m = 0; m < 4; ++m) {
#pragma unroll
    for (int n = 0; n < 4; ++n) {
      int col = col0 + wc * 64 + n * 16 + lrow;
      if (col < N) {
#pragma unroll
        for (int i = 0; i < 4; ++i) {
          int row = row0 + wr * 64 + m * 16 + lkg * 4 + i;
          size_t idx = (size_t)row * N + col;
          if (OUT_BF16) ((u16*)Cv)[idx] = f2bf(acc[m][n][i]);
          else          ((float*)Cv)[idx] = acc[m][n][i];
        }
      }
    }
  }
}

// ---------------- causal flash attention v5: 1 block/CU, 8 waves x 32 q-rows ----------------
// grid (h=32, qb=8) = 256 blocks = exactly 1/CU; 512 thr = 8 waves = 2/SIMD for the
// block's whole life (no solo-degradation mode; tail CUs just idle). Block owns
// 256 q-rows (qb*256..+256); wave w owns rows qb*256+w*32..+32 as two 16-row halves
// -> each K/V LDS fragment feeds 2 MFMAs (LDS-BW per MFMA halved vs r9; r9 measured
// LDS-bound: 4w x 42reads x 1KB x 66it x 2blk / 85B/cyc ~= 111us of 129).
// K/V double-buffered via global_load_lds in fragment order, 5 chunks/wave of 40;
// counted vmcnt(5) keeps next-tile prefetch in flight across raw s_barriers (T4).
// Trailing raw barrier safe: ds_reads are lgkmcnt-drained before their MFMAs.
// bid%8 = h%8 -> head-pinned XCD (32 blocks/XCD = 32 CUs/XCD). defer-max + deferred-l.
__global__ __launch_bounds__(512, 2) void mla_attn_kernel(const u16* __restrict__ qf,
                                                          const u16* __restrict__ kf,
                                                          const u16* __restrict__ vT,
                                                          u16* __restrict__ o) {
  const int h = blockIdx.x, qb = blockIdx.y;
  const int t = threadIdx.x, wave = t >> 6, lane = t & 63;
  const int lrow = lane & 15, lkg = lane >> 4;
  __shared__ __align__(16) u16 Kt[2][24 * 512];   // (cg,kk): K[cg*16+l&15][kk*32+(l>>4)*8]
  __shared__ __align__(16) u16 Vt[2][16 * 512];   // (f,ck):  vT[f*16+l&15][ck*32+(l>>4)*8]
  __shared__ __align__(16) u16 Pl[8][32][72];

  // ---- staging setup: 40 chunks (24 K + 16 V) split 5/wave ----
  const u16* src0[5]; int step[5]; u16 *dst0[5], *dst1[5];
#pragma unroll
  for (int i = 0; i < 5; ++i) {
    int c = wave * 5 + i;
    if (c < 24) {
      int cg = c / 6, kk = c - cg * 6;
      src0[i] = kf + ((size_t)h * 2048 + cg * 16 + lrow) * 192 + kk * 32 + lkg * 8;
      step[i] = 192;
      dst0[i] = &Kt[0][(cg * 6 + kk) * 512];
      dst1[i] = &Kt[1][(cg * 6 + kk) * 512];
    } else {
      int j = c - 24, f = j >> 1, ck = j & 1;
      src0[i] = vT + ((size_t)h * 128 + f * 16 + lrow) * 2048 + ck * 32 + lkg * 8;
      step[i] = 1;
      dst0[i] = &Vt[0][(f * 2 + ck) * 512];
      dst1[i] = &Vt[1][(f * 2 + ck) * 512];
    }
  }

  const int qbase = qb * 256 + wave * 32;

  // Q fragments: 2 row-halves x 6 k-chunks
  bf16x8 qfr[2][6];
#pragma unroll
  for (int r = 0; r < 2; ++r) {
    const u16* qp = qf + ((size_t)h * 2048 + qbase + r * 16 + lrow) * 192 + lkg * 8;
#pragma unroll
    for (int kk = 0; kk < 6; ++kk)
      qfr[r][kk] = *reinterpret_cast<const bf16x8*>(qp + kk * 32);
  }

  f32x4 acc[2][8];
#pragma unroll
  for (int r = 0; r < 2; ++r)
#pragma unroll
    for (int f = 0; f < 8; ++f) acc[r][f] = 0.f;
  float m_run[2][4], l_par[2][4];
#pragma unroll
  for (int r = 0; r < 2; ++r)
#pragma unroll
    for (int i = 0; i < 4; ++i) { m_run[r][i] = -1e30f; l_par[r][i] = 0.f; }

  const int nt = qb * 4 + 4;   // KV tiles of 64

  // prologue: tile 0 -> buf 0
#pragma unroll
  for (int i = 0; i < 5; ++i) gload16(src0[i], dst0[i]);

  for (int it = 0; it < nt; ++it) {
    const int kt = it * 64;
    if (it + 1 < nt) {   // prefetch next tile into other buffer
      const size_t adv = (size_t)(kt + 64);
      const int nb = (it + 1) & 1;
#pragma unroll
      for (int i = 0; i < 5; ++i)
        gload16(src0[i] + adv * step[i], nb ? dst1[i] : dst0[i]);
      asm volatile("s_waitcnt vmcnt(5)" ::: "memory");  // current tile landed; prefetch in flight
    } else {
      asm volatile("s_waitcnt vmcnt(0)" ::: "memory");
    }
    __builtin_amdgcn_s_barrier();
    __builtin_amdgcn_sched_barrier(0);

    const u16* Kb = &Kt[it & 1][0];
    const u16* Vb = &Vt[it & 1][0];
    if (kt <= qbase + 31) {   // wave-uniform: skip fully-masked tiles
      // ---- S = Q K^T: 48 MFMA on 24 K-fragment reads (2x reuse) ----
      f32x4 sv[2][4];
#pragma unroll
      for (int r = 0; r < 2; ++r)
#pragma unroll
        for (int cg = 0; cg < 4; ++cg) sv[r][cg] = 0.f;
#pragma unroll
      for (int cg = 0; cg < 4; ++cg)
#pragma unroll
        for (int kk = 0; kk < 6; ++kk) {
          bf16x8 kfr = *reinterpret_cast<const bf16x8*>(&Kb[(cg * 6 + kk) * 512 + lane * 8]);
          sv[0][cg] = __builtin_amdgcn_mfma_f32_16x16x32_bf16(qfr[0][kk], kfr, sv[0][cg], 0, 0, 0);
          sv[1][cg] = __builtin_amdgcn_mfma_f32_16x16x32_bf16(qfr[1][kk], kfr, sv[1][cg], 0, 0, 0);
        }

      // ---- causal mask (diagonal region of this wave only) ----
      if (kt + 63 > qbase) {
#pragma unroll
        for (int r = 0; r < 2; ++r)
#pragma unroll
          for (int cg = 0; cg < 4; ++cg) {
            int kvcol = kt + cg * 16 + lrow;
            int rowb = qbase + r * 16 + lkg * 4;
#pragma unroll
            for (int i = 0; i < 4; ++i)
              if (kvcol > rowb + i) sv[r][cg][i] = -__builtin_inff();
          }
      }

      // ---- softmax per row-half: defer-max + deferred-l ----
#pragma unroll
      for (int r = 0; r < 2; ++r) {
        float tmax[4];
#pragma unroll
        for (int i = 0; i < 4; ++i)
          tmax[i] = fmaxf(fmaxf(sv[r][0][i], sv[r][1][i]), fmaxf(sv[r][2][i], sv[r][3][i]));
#pragma unroll
        for (int m = 8; m >= 1; m >>= 1)
#pragma unroll
          for (int i = 0; i < 4; ++i) tmax[i] = fmaxf(tmax[i], __shfl_xor(tmax[i], m));
        int need = 0;
#pragma unroll
        for (int i = 0; i < 4; ++i) need |= (tmax[i] > m_run[r][i] + 8.f) ? 1 : 0;
        if (__any(need)) {
#pragma unroll
          for (int i = 0; i < 4; ++i) {
            float mnew = fmaxf(m_run[r][i], tmax[i]);
            float alpha = __expf(m_run[r][i] - mnew);
            m_run[r][i] = mnew;
            l_par[r][i] *= alpha;
#pragma unroll
            for (int f = 0; f < 8; ++f) acc[r][f][i] *= alpha;
          }
        }
#pragma unroll
        for (int i = 0; i < 4; ++i) {
#pragma unroll
          for (int cg = 0; cg < 4; ++cg) sv[r][cg][i] = __expf(sv[r][cg][i] - m_run[r][i]);
          l_par[r][i] += (sv[r][0][i] + sv[r][1][i]) + (sv[r][2][i] + sv[r][3][i]);
        }
        // P -> bf16 -> per-wave LDS
#pragma unroll
        for (int cg = 0; cg < 4; ++cg)
#pragma unroll
          for (int i = 0; i < 4; ++i)
            Pl[wave][r * 16 + lkg * 4 + i][cg * 16 + lrow] = f2bf(sv[r][cg][i]);
      }

      // ---- O += P V: 32 MFMA on 16 V-fragment reads (2x reuse) ----
#pragma unroll
      for (int ck = 0; ck < 2; ++ck) {
        bf16x8 pf0 = *reinterpret_cast<const bf16x8*>(&Pl[wave][lrow][ck * 32 + lkg * 8]);
        bf16x8 pf1 = *reinterpret_cast<const bf16x8*>(&Pl[wave][16 + lrow][ck * 32 + lkg * 8]);
#pragma unroll
        for (int f = 0; f < 8; ++f) {
          bf16x8 vfr = *reinterpret_cast<const bf16x8*>(&Vb[(f * 2 + ck) * 512 + lane * 8]);
          acc[0][f] = __builtin_amdgcn_mfma_f32_16x16x32_bf16(pf0, vfr, acc[0][f], 0, 0, 0);
          acc[1][f] = __builtin_amdgcn_mfma_f32_16x16x32_bf16(pf1, vfr, acc[1][f], 0, 0, 0);
        }
      }
    }
    __builtin_amdgcn_sched_barrier(0);
    __builtin_amdgcn_s_barrier();   // all waves done reading this buf before it is restaged
  }

  // ---- epilogue: one l reduce, divide, store ----
#pragma unroll
  for (int r = 0; r < 2; ++r)
#pragma unroll
    for (int i = 0; i < 4; ++i)
#pragma unroll
      for (int m = 8; m >= 1; m >>= 1) l_par[r][i] += __shfl_xor(l_par[r][i], m);
#pragma unroll
  for (int r = 0; r < 2; ++r)
#pragma unroll
    for (int f = 0; f < 8; ++f)
#pragma unroll
      for (int i = 0; i < 4; ++i) {
        int row = qbase + r * 16 + lkg * 4 + i;
        int col = h * 128 + f * 16 + lrow;
        o[(size_t)row * 4096 + col] = f2bf(acc[r][f][i] / l_par[r][i]);
      }
}

// ---------------------------------------------------------------
extern "C" void kernel_launch(void* const* d_in, const int* in_sizes, int n_in,
                              void* d_out, int out_size, void* d_ws, size_t ws_size,
                              hipStream_t stream) {
  (void)in_sizes; (void)n_in; (void)out_size; (void)ws_size;
  const float* hs   = (const float*)d_in[0];
  const float* Wqa  = (const float*)d_in[1];
  const float* qln  = (const float*)d_in[2];
  const float* Wqb  = (const float*)d_in[3];
  const float* Wkva = (const float*)d_in[4];
  const float* kvln = (const float*)d_in[5];
  const float* Wkvb = (const float*)d_in[6];
  const float* Wo   = (const float*)d_in[7];
  float* out = (float*)d_out;

  char* p = (char*)d_ws;
  size_t off = 0;
  auto carve = [&](size_t bytes) {
    char* r = p + off;
    off += (bytes + 255) & ~(size_t)255;
    return r;
  };
  u16* hs_bf = (u16*)carve((size_t)2048 * 4096 * 2);
  u16* WabT  = (u16*)carve((size_t)2112 * 4096 * 2);   // [0..1535]=WqaT, [1536..2111]=WkvaT
  u16* WqbT  = (u16*)carve((size_t)6144 * 1536 * 2);
  u16* WkvbT = (u16*)carve((size_t)8192 * 512 * 2);
  u16* WoT   = (u16*)carve((size_t)4096 * 4096 * 2);
  u16* fused = (u16*)carve((size_t)2048 * 2112 * 2);   // [qa | ckv] per row
  u16* qan   = (u16*)carve((size_t)2048 * 1536 * 2);
  u16* q     = (u16*)carve((size_t)2048 * 6144 * 2);
  u16* cn    = (u16*)carve((size_t)2048 * 512 * 2);
  u16* kv    = (u16*)carve((size_t)2048 * 8192 * 2);
  u16* qfb   = (u16*)carve((size_t)32 * 2048 * 192 * 2);
  u16* kfb   = (u16*)carve((size_t)32 * 2048 * 192 * 2);
  u16* vTb   = (u16*)carve((size_t)32 * 128 * 2048 * 2);
  u16* ob    = (u16*)carve((size_t)2048 * 4096 * 2);
  float* cost = (float*)carve((size_t)65536 * 4);
  float* sint = (float*)carve((size_t)65536 * 4);

  // --- prep: casts / transposes / tables ---
  cast_bf16_kernel<<<8192, 256, 0, stream>>>(hs, hs_bf, 2048 * 4096);
  transpose_cast_kernel<<<dim3(24, 64), 256, 0, stream>>>(Wqa, WabT, 4096, 1536);
  transpose_cast_kernel<<<dim3(9, 64), 256, 0, stream>>>(Wkva, WabT + (size_t)1536 * 4096, 4096, 576);
  transpose_cast_kernel<<<dim3(96, 24), 256, 0, stream>>>(Wqb, WqbT, 1536, 6144);
  transpose_cast_kernel<<<dim3(128, 8), 256, 0, stream>>>(Wkvb, WkvbT, 512, 8192);
  transpose_cast_kernel<<<dim3(64, 64), 256, 0, stream>>>(Wo, WoT, 4096, 4096);
  rope_table_kernel<<<256, 256, 0, stream>>>(cost, sint);

  // --- fused first-stage GEMM: [qa | ckv] = hs @ [Wqa | Wkva] ---
  gemm_v3_kernel<1><<<dim3(17, 16), 256, 0, stream>>>(hs_bf, WabT, fused, 2048, 2112, 4096);

  // --- norms ---
  rmsnorm_kernel<<<2048, 256, 0, stream>>>(fused, qln, qan, 1536, 2112, 1536);
  rmsnorm_kernel<<<2048, 256, 0, stream>>>(fused + 1536, kvln, cn, 512, 2112, 512);

  // --- second-stage GEMMs ---
  gemm_v3_kernel<1><<<dim3(48, 16), 256, 0, stream>>>(qan, WqbT, q, 2048, 6144, 1536);
  gemm_v3_kernel<1><<<dim3(64, 16), 256, 0, stream>>>(cn, WkvbT, kv, 2048, 8192, 512);

  // --- head-major layouts + RoPE (vectorized) ---
  build_qf_kernel<<<6144, 256, 0, stream>>>(q, cost, sint, qfb);
  build_kf_kernel<<<6144, 256, 0, stream>>>(kv, fused + 1536, cost, sint, kfb);
  vt_build_kernel<<<dim3(32, 2, 32), 256, 0, stream>>>(kv, vTb);

  // --- attention (256 blocks of 512 thr, 1/CU, 8 waves, dbuf + counted vmcnt) ---
  mla_attn_kernel<<<dim3(32, 8), 512, 0, stream>>>(qfb, kfb, vTb, ob);

  // --- output projection ---
  gemm_v3_kernel<0><<<dim3(32, 16), 256, 0, stream>>>(ob, WoT, out, 2048, 4096, 4096);
}

// Round 12
// 427.136 us; speedup vs baseline: 1.0961x; 1.0961x over previous
//
#include <hip/hip_runtime.h>

typedef unsigned short u16;
using bf16x8 = __attribute__((ext_vector_type(8))) __bf16;
using f32x4  = __attribute__((ext_vector_type(4))) float;
using s16x8  = __attribute__((ext_vector_type(8))) short;
using s16x4  = __attribute__((ext_vector_type(4))) short;

#define AS1 __attribute__((address_space(1)))
#define AS3 __attribute__((address_space(3)))

__device__ __forceinline__ void gload16(const u16* g, u16* l) {
  __builtin_amdgcn_global_load_lds((AS1 void*)(size_t)g, (AS3 void*)l, 16, 0, 0);
}

__device__ __forceinline__ u16 f2bf(float f) {
  unsigned u = __float_as_uint(f);
  u += 0x7fffu + ((u >> 16) & 1u);   // round-to-nearest-even
  return (u16)(u >> 16);
}
__device__ __forceinline__ float bf2f(u16 h) {
  return __uint_as_float(((unsigned)h) << 16);
}

// ---------------- elementwise f32 -> bf16 ----------------
__global__ __launch_bounds__(256) void cast_bf16_kernel(const float* __restrict__ x,
                                                        u16* __restrict__ y, int n) {
  int i = (blockIdx.x * 256 + threadIdx.x) * 4;
  if (i + 3 < n) {
    float4 v = *reinterpret_cast<const float4*>(x + i);
    s16x4 o;
    o[0] = (short)f2bf(v.x); o[1] = (short)f2bf(v.y);
    o[2] = (short)f2bf(v.z); o[3] = (short)f2bf(v.w);
    *reinterpret_cast<s16x4*>(y + i) = o;
  }
}

// ---------------- W [K][N] f32 -> WT [N][K] bf16 (64x64 tiles) ----------------
__global__ __launch_bounds__(256) void transpose_cast_kernel(const float* __restrict__ W,
                                                             u16* __restrict__ WT,
                                                             int K, int N) {
  __shared__ u16 tile[64][72];
  const int t = threadIdx.x;
  const int nb = blockIdx.x * 64, kb = blockIdx.y * 64;
  const int rr = t >> 3;        // 0..31
  const int cc = (t & 7) * 8;   // 0..56
#pragma unroll
  for (int pass = 0; pass < 2; ++pass) {
    const float* src = W + (size_t)(kb + pass * 32 + rr) * N + nb + cc;
    float4 a = *reinterpret_cast<const float4*>(src);
    float4 b = *reinterpret_cast<const float4*>(src + 4);
    u16* tr = &tile[pass * 32 + rr][cc];
    tr[0] = f2bf(a.x); tr[1] = f2bf(a.y); tr[2] = f2bf(a.z); tr[3] = f2bf(a.w);
    tr[4] = f2bf(b.x); tr[5] = f2bf(b.y); tr[6] = f2bf(b.z); tr[7] = f2bf(b.w);
  }
  __syncthreads();
#pragma unroll
  for (int pass = 0; pass < 2; ++pass) {
    s16x8 v;
#pragma unroll
    for (int j = 0; j < 8; ++j) v[j] = (short)tile[cc + j][pass * 32 + rr];
    *reinterpret_cast<s16x8*>(WT + (size_t)(nb + pass * 32 + rr) * K + kb + cc) = v;
  }
}

// ---------------- RMSNorm (bf16 in/out, f32 weight) ----------------
__global__ __launch_bounds__(256) void rmsnorm_kernel(const u16* __restrict__ x,
                                                      const float* __restrict__ w,
                                                      u16* __restrict__ y,
                                                      int R, int xs, int ys) {
  const int row = blockIdx.x, t = threadIdx.x;
  const u16* xr = x + (size_t)row * xs;
  float ss = 0.f;
  for (int i = t; i < R; i += 256) { float f = bf2f(xr[i]); ss += f * f; }
#pragma unroll
  for (int m = 32; m >= 1; m >>= 1) ss += __shfl_xor(ss, m);
  __shared__ float red[4];
  if ((t & 63) == 0) red[t >> 6] = ss;
  __syncthreads();
  float tot = red[0] + red[1] + red[2] + red[3];
  float r = rsqrtf(tot / (float)R + 1e-6f);
  u16* yr = y + (size_t)row * ys;
  for (int i = t; i < R; i += 256) yr[i] = f2bf(bf2f(xr[i]) * r * w[i]);
}

// ---------------- RoPE cos/sin table: [2048][32] each ----------------
__global__ __launch_bounds__(256) void rope_table_kernel(float* __restrict__ cost,
                                                         float* __restrict__ sint) {
  int idx = blockIdx.x * 256 + threadIdx.x;   // 65536
  int pos = idx >> 5, j = idx & 31;
  float inv = __expf(-(float)j * (9.210340371976184f / 32.0f));  // 10000^(-j/32)
  float f = (float)pos * inv;
  cost[idx] = cosf(f);
  sint[idx] = sinf(f);
}

// ---------------- qf build (vectorized): q [s][h*192] -> qf [h][s][192], RoPE + scale ----------------
__global__ __launch_bounds__(256) void build_qf_kernel(const u16* __restrict__ q,
                                                       const float* __restrict__ cost,
                                                       const float* __restrict__ sint,
                                                       u16* __restrict__ qf) {
  int tid = blockIdx.x * 256 + threadIdx.x;
  int o8 = tid * 8;
  if (o8 >= 32 * 2048 * 192) return;
  const float scale = 0.07216878364870323f;  // 192^-0.5 (folded into q)
  int c = (o8 % 192) >> 3;  // chunk 0..23
  int rest = o8 / 192;
  int s = rest & 2047, h = rest >> 11;
  const u16* qrow = q + ((size_t)s * 32 + h) * 192;
  s16x8 out;
  if (c < 16) {
    s16x8 v = *reinterpret_cast<const s16x8*>(qrow + c * 8);
#pragma unroll
    for (int j = 0; j < 8; ++j) out[j] = (short)f2bf(bf2f((u16)v[j]) * scale);
  } else {
    int j0 = c * 8 - 128;
    bool lo = j0 < 32;
    int jj0 = lo ? j0 : j0 - 32;
    s16x8 a = *reinterpret_cast<const s16x8*>(qrow + 128 + 2 * jj0);
    s16x8 b = *reinterpret_cast<const s16x8*>(qrow + 128 + 2 * jj0 + 8);
    float4 c0 = *reinterpret_cast<const float4*>(cost + s * 32 + jj0);
    float4 c1 = *reinterpret_cast<const float4*>(cost + s * 32 + jj0 + 4);
    float4 s0 = *reinterpret_cast<const float4*>(sint + s * 32 + jj0);
    float4 s1 = *reinterpret_cast<const float4*>(sint + s * 32 + jj0 + 4);
    float cs[8] = {c0.x, c0.y, c0.z, c0.w, c1.x, c1.y, c1.z, c1.w};
    float sn[8] = {s0.x, s0.y, s0.z, s0.w, s1.x, s1.y, s1.z, s1.w};
#pragma unroll
    for (int j = 0; j < 8; ++j) {
      float x0 = bf2f((u16)((j < 4) ? a[2 * j] : b[2 * j - 8]));
      float x1 = bf2f((u16)((j < 4) ? a[2 * j + 1] : b[2 * j - 7]));
      float v = lo ? (x0 * cs[j] - x1 * sn[j]) : (x1 * cs[j] + x0 * sn[j]);
      out[j] = (short)f2bf(v * scale);
    }
  }
  *reinterpret_cast<s16x8*>(qf + o8) = out;
}

// ---------------- kf RoPE-only build: ckv(stride 2112) -> kf [h][s][128..192) ----------------
__global__ __launch_bounds__(256) void build_kf_rope_kernel(const u16* __restrict__ ckv,
                                                            const float* __restrict__ cost,
                                                            const float* __restrict__ sint,
                                                            u16* __restrict__ kf) {
  int tid = blockIdx.x * 256 + threadIdx.x;
  int o8 = tid * 8;
  if (o8 >= 32 * 2048 * 64) return;
  int j0 = o8 & 63;
  int rest = o8 >> 6;
  int s = rest & 2047, h = rest >> 11;
  bool lo = j0 < 32;
  int jj0 = lo ? j0 : j0 - 32;
  const u16* crow = ckv + (size_t)s * 2112 + 512;
  s16x8 a = *reinterpret_cast<const s16x8*>(crow + 2 * jj0);
  s16x8 b = *reinterpret_cast<const s16x8*>(crow + 2 * jj0 + 8);
  float4 c0 = *reinterpret_cast<const float4*>(cost + s * 32 + jj0);
  float4 c1 = *reinterpret_cast<const float4*>(cost + s * 32 + jj0 + 4);
  float4 s0 = *reinterpret_cast<const float4*>(sint + s * 32 + jj0);
  float4 s1 = *reinterpret_cast<const float4*>(sint + s * 32 + jj0 + 4);
  float cs[8] = {c0.x, c0.y, c0.z, c0.w, c1.x, c1.y, c1.z, c1.w};
  float sn[8] = {s0.x, s0.y, s0.z, s0.w, s1.x, s1.y, s1.z, s1.w};
  s16x8 out;
#pragma unroll
  for (int j = 0; j < 8; ++j) {
    float x0 = bf2f((u16)((j < 4) ? a[2 * j] : b[2 * j - 8]));
    float x1 = bf2f((u16)((j < 4) ? a[2 * j + 1] : b[2 * j - 7]));
    float v = lo ? (x0 * cs[j] - x1 * sn[j]) : (x1 * cs[j] + x0 * sn[j]);
    out[j] = (short)f2bf(v);
  }
  *reinterpret_cast<s16x8*>(kf + ((size_t)h * 2048 + s) * 192 + 128 + j0) = out;
}

// ---------------- GEMM v3: C[M][N] = A[M][K](bf16) * BT[N][K](bf16)^T ----------------
// 128x128 tile, BK=32, 4 waves (2x2). 4-deep LDS pipeline, prefetch distance 3,
// one raw s_barrier/iter with counted vmcnt(8), XOR-swizzled LDS, setprio MFMA.
// EPI: 0 = f32 C, 1 = bf16 C, 2 = MLA-kv split epilogue (kf nope + vT direct).
template <int EPI>
__global__ __launch_bounds__(256) void gemm_v3_kernel(const u16* __restrict__ A,
                                                      const u16* __restrict__ BT,
                                                      void* __restrict__ Cv,
                                                      void* __restrict__ Cv2,
                                                      int M, int N, int K) {
  __shared__ __align__(16) u16 S[4 * 8192];
  const int t0 = threadIdx.x;
  const int lane = t0 & 63, wave = t0 >> 6;
  const int wr = wave >> 1, wc = wave & 1;
  const int row0 = blockIdx.y * 128, col0 = blockIdx.x * 128;
  const int lrow = lane & 15, lkg = lane >> 4;

  const int lp = lane ^ ((lane >> 3) & 3);
  const int srow_off = lp >> 2;
  const int skel = (lp & 3) * 8;
  const int c0 = wave * 2, c1 = c0 + 1;
  const int arow_c0 = row0 + c0 * 16 + srow_off;
  const int arow_c1 = row0 + c1 * 16 + srow_off;
  int brow_c0 = col0 + c0 * 16 + srow_off; if (brow_c0 > N - 1) brow_c0 = N - 1;
  int brow_c1 = col0 + c1 * 16 + srow_off; if (brow_c1 > N - 1) brow_c1 = N - 1;

  int aoff[4], boff[4];
#pragma unroll
  for (int m = 0; m < 4; ++m) {
    int r = wr * 64 + m * 16 + lrow;
    int off = r * 32 + lkg * 8;
    aoff[m] = off ^ ((off >> 3) & 0x18);
    r = wc * 64 + m * 16 + lrow;
    off = r * 32 + lkg * 8;
    boff[m] = off ^ ((off >> 3) & 0x18);
  }

  const int NT = K >> 5;

#pragma unroll
  for (int pt = 0; pt < 3; ++pt) {
    u16* ab = &S[pt * 8192];
    const int kb = pt * 32 + skel;
    gload16(A  + (size_t)arow_c0 * K + kb, ab + c0 * 512);
    gload16(A  + (size_t)arow_c1 * K + kb, ab + c1 * 512);
    gload16(BT + (size_t)brow_c0 * K + kb, ab + 4096 + c0 * 512);
    gload16(BT + (size_t)brow_c1 * K + kb, ab + 4096 + c1 * 512);
  }

  f32x4 acc[4][4];
#pragma unroll
  for (int m = 0; m < 4; ++m)
#pragma unroll
    for (int n = 0; n < 4; ++n) acc[m][n] = 0.f;

  for (int t = 0; t < NT; ++t) {
    if (t + 2 < NT)      asm volatile("s_waitcnt vmcnt(8)" ::: "memory");
    else if (t + 1 < NT) asm volatile("s_waitcnt vmcnt(4)" ::: "memory");
    else                 asm volatile("s_waitcnt vmcnt(0)" ::: "memory");
    __builtin_amdgcn_s_barrier();
    __builtin_amdgcn_sched_barrier(0);

    const u16* ab = &S[(t & 3) * 8192];
    bf16x8 af[4], bb[4];
#pragma unroll
    for (int m = 0; m < 4; ++m)
      af[m] = *reinterpret_cast<const bf16x8*>(ab + aoff[m]);
#pragma unroll
    for (int n = 0; n < 4; ++n)
      bb[n] = *reinterpret_cast<const bf16x8*>(ab + 4096 + boff[n]);

    if (t + 3 < NT) {
      u16* sb = &S[((t + 3) & 3) * 8192];
      const int kb = (t + 3) * 32 + skel;
      gload16(A  + (size_t)arow_c0 * K + kb, sb + c0 * 512);
      gload16(A  + (size_t)arow_c1 * K + kb, sb + c1 * 512);
      gload16(BT + (size_t)brow_c0 * K + kb, sb + 4096 + c0 * 512);
      gload16(BT + (size_t)brow_c1 * K + kb, sb + 4096 + c1 * 512);
    }

    __builtin_amdgcn_s_setprio(1);
#pragma unroll
    for (int m = 0; m < 4; ++m)
#pragma unroll
      for (int n = 0; n < 4; ++n)
        acc[m][n] = __builtin_amdgcn_mfma_f32_16x16x32_bf16(af[m], bb[n], acc[m][n], 0, 0, 0);
    __builtin_amdgcn_s_setprio(0);
  }

#pragma unroll
  for (int m = 0; m < 4; ++m) {
#pragma unroll
    for (int n = 0; n < 4; ++n) {
      int col = col0 + wc * 64 + n * 16 + lrow;
      int row = row0 + wr * 64 + m * 16 + lkg * 4;
      if (EPI == 2) {
        // MLA kv split: col = h*256 + d. d<128 -> kf[h][row][d]; d>=128 -> vT[h][d-128][row..row+3]
        int d = col & 255, hh = col >> 8;
        if (d < 128) {
          u16* dst = (u16*)Cv + ((size_t)hh * 2048 + row) * 192 + d;
#pragma unroll
          for (int i = 0; i < 4; ++i) dst[(size_t)i * 192] = f2bf(acc[m][n][i]);
        } else {
          s16x4 v;
#pragma unroll
          for (int i = 0; i < 4; ++i) v[i] = (short)f2bf(acc[m][n][i]);
          *reinterpret_cast<s16x4*>((u16*)Cv2 + ((size_t)hh * 128 + (d - 128)) * 2048 + row) = v;
        }
      } else if (col < N) {
#pragma unroll
        for (int i = 0; i < 4; ++i) {
          size_t idx = (size_t)(row + i) * N + col;
          if (EPI == 1) ((u16*)Cv)[idx] = f2bf(acc[m][n][i]);
          else          ((float*)Cv)[idx] = acc[m][n][i];
        }
      }
    }
  }
}

// ---------------- causal flash attention (round-9 version: best known, 129us) ----------------
// grid (h=32, pair=16): bid%8 = h%8 pins each head's K/V to one XCD L2.
// 512 blocks = 2/CU (cross-block overlap hides staging). Block handles qb=pair
// and qb=31-pair (constant 33 KV-64 iterations). 256 thr = 4 waves; wave w owns
// q rows qb*64+w*16..+16. K/V staged to LDS in fragment order via global_load_lds.
// T13 defer-max + deferred-l.
__global__ __launch_bounds__(256) void mla_attn_kernel(const u16* __restrict__ qf,
                                                       const u16* __restrict__ kf,
                                                       const u16* __restrict__ vT,
                                                       u16* __restrict__ o) {
  const int h = blockIdx.x, pair = blockIdx.y;
  const int t = threadIdx.x, wave = t >> 6, lane = t & 63;
  const int lrow = lane & 15, lkg = lane >> 4;
  __shared__ __align__(16) u16 Kt[24 * 512];   // (cg,kk): K[cg*16+l&15][kk*32+(l>>4)*8]
  __shared__ __align__(16) u16 Vt[16 * 512];   // (f,ck):  vT[f*16+l&15][ck*32+(l>>4)*8]
  __shared__ __align__(16) u16 Pl[4][16][72];

  const u16* ksrc0 = kf + ((size_t)h * 2048 + wave * 16 + lrow) * 192 + lkg * 8;
  const u16* vsrc0 = vT + ((size_t)h * 128 + wave * 32 + lrow) * 2048 + lkg * 8;

  for (int qq = 0; qq < 2; ++qq) {
    const int qb = qq ? (31 - pair) : pair;
    const int qbase = qb * 64 + wave * 16;

    bf16x8 qfr[6];
    const u16* qrow_ptr = qf + ((size_t)h * 2048 + qbase + lrow) * 192;
#pragma unroll
    for (int kk = 0; kk < 6; ++kk)
      qfr[kk] = *reinterpret_cast<const bf16x8*>(qrow_ptr + kk * 32 + lkg * 8);

    f32x4 acc_o[8];
#pragma unroll
    for (int f = 0; f < 8; ++f) acc_o[f] = 0.f;
    float m_run[4], l_par[4];
#pragma unroll
    for (int i = 0; i < 4; ++i) { m_run[i] = -1e30f; l_par[i] = 0.f; }

    const int kv_end = qb * 64 + 64;
    for (int kt = 0; kt < kv_end; kt += 64) {
      {
        const u16* ks = ksrc0 + (size_t)kt * 192;
#pragma unroll
        for (int kk = 0; kk < 6; ++kk)
          gload16(ks + kk * 32, &Kt[(wave * 6 + kk) * 512]);
#pragma unroll
        for (int j = 0; j < 4; ++j) {
          int fo = (j >> 1), ck = j & 1;
          gload16(vsrc0 + (size_t)fo * 16 * 2048 + kt + ck * 32,
                  &Vt[((wave * 2 + fo) * 2 + ck) * 512]);
        }
      }
      __syncthreads();

      f32x4 sv[4];
#pragma unroll
      for (int cg = 0; cg < 4; ++cg) sv[cg] = 0.f;
#pragma unroll
      for (int cg = 0; cg < 4; ++cg)
#pragma unroll
        for (int kk = 0; kk < 6; ++kk) {
          bf16x8 kfr = *reinterpret_cast<const bf16x8*>(&Kt[(cg * 6 + kk) * 512 + lane * 8]);
          sv[cg] = __builtin_amdgcn_mfma_f32_16x16x32_bf16(qfr[kk], kfr, sv[cg], 0, 0, 0);
        }

      const int qrow_b = qbase + lkg * 4;
      if (kt + 64 >= kv_end) {
#pragma unroll
        for (int cg = 0; cg < 4; ++cg) {
          int kvcol = kt + cg * 16 + lrow;
#pragma unroll
          for (int i = 0; i < 4; ++i)
            if (kvcol > qrow_b + i) sv[cg][i] = -__builtin_inff();
        }
      }
      // ---- softmax: defer-max + deferred-l ----
      float tmax[4];
#pragma unroll
      for (int i = 0; i < 4; ++i)
        tmax[i] = fmaxf(fmaxf(sv[0][i], sv[1][i]), fmaxf(sv[2][i], sv[3][i]));
#pragma unroll
      for (int m = 8; m >= 1; m >>= 1)
#pragma unroll
        for (int i = 0; i < 4; ++i) tmax[i] = fmaxf(tmax[i], __shfl_xor(tmax[i], m));
      int need = 0;
#pragma unroll
      for (int i = 0; i < 4; ++i) need |= (tmax[i] > m_run[i] + 8.f) ? 1 : 0;
      if (__any(need)) {
#pragma unroll
        for (int i = 0; i < 4; ++i) {
          float mnew = fmaxf(m_run[i], tmax[i]);
          float alpha = __expf(m_run[i] - mnew);
          m_run[i] = mnew;
          l_par[i] *= alpha;
#pragma unroll
          for (int f = 0; f < 8; ++f) acc_o[f][i] *= alpha;
        }
      }
#pragma unroll
      for (int i = 0; i < 4; ++i) {
#pragma unroll
        for (int cg = 0; cg < 4; ++cg) sv[cg][i] = __expf(sv[cg][i] - m_run[i]);
        l_par[i] += (sv[0][i] + sv[1][i]) + (sv[2][i] + sv[3][i]);
      }
      // ---- P -> bf16 -> per-wave LDS ----
#pragma unroll
      for (int cg = 0; cg < 4; ++cg)
#pragma unroll
        for (int i = 0; i < 4; ++i)
          Pl[wave][lkg * 4 + i][cg * 16 + lrow] = f2bf(sv[cg][i]);
      // ---- O += P V (V from LDS) ----
#pragma unroll
      for (int ck = 0; ck < 2; ++ck) {
        bf16x8 pf = *reinterpret_cast<const bf16x8*>(&Pl[wave][lrow][ck * 32 + lkg * 8]);
#pragma unroll
        for (int f = 0; f < 8; ++f) {
          bf16x8 vfr = *reinterpret_cast<const bf16x8*>(&Vt[(f * 2 + ck) * 512 + lane * 8]);
          acc_o[f] = __builtin_amdgcn_mfma_f32_16x16x32_bf16(pf, vfr, acc_o[f], 0, 0, 0);
        }
      }
      __syncthreads();
    }
    // ---- epilogue: one l reduce, divide, store ----
#pragma unroll
    for (int i = 0; i < 4; ++i)
#pragma unroll
      for (int m = 8; m >= 1; m >>= 1) l_par[i] += __shfl_xor(l_par[i], m);
#pragma unroll
    for (int f = 0; f < 8; ++f)
#pragma unroll
      for (int i = 0; i < 4; ++i) {
        int row = qbase + lkg * 4 + i;
        int col = h * 128 + f * 16 + lrow;
        o[(size_t)row * 4096 + col] = f2bf(acc_o[f][i] / l_par[i]);
      }
  }
}

// ---------------------------------------------------------------
extern "C" void kernel_launch(void* const* d_in, const int* in_sizes, int n_in,
                              void* d_out, int out_size, void* d_ws, size_t ws_size,
                              hipStream_t stream) {
  (void)in_sizes; (void)n_in; (void)out_size; (void)ws_size;
  const float* hs   = (const float*)d_in[0];
  const float* Wqa  = (const float*)d_in[1];
  const float* qln  = (const float*)d_in[2];
  const float* Wqb  = (const float*)d_in[3];
  const float* Wkva = (const float*)d_in[4];
  const float* kvln = (const float*)d_in[5];
  const float* Wkvb = (const float*)d_in[6];
  const float* Wo   = (const float*)d_in[7];
  float* out = (float*)d_out;

  char* p = (char*)d_ws;
  size_t off = 0;
  auto carve = [&](size_t bytes) {
    char* r = p + off;
    off += (bytes + 255) & ~(size_t)255;
    return r;
  };
  u16* hs_bf = (u16*)carve((size_t)2048 * 4096 * 2);
  u16* WabT  = (u16*)carve((size_t)2112 * 4096 * 2);   // [0..1535]=WqaT, [1536..2111]=WkvaT
  u16* WqbT  = (u16*)carve((size_t)6144 * 1536 * 2);
  u16* WkvbT = (u16*)carve((size_t)8192 * 512 * 2);
  u16* WoT   = (u16*)carve((size_t)4096 * 4096 * 2);
  u16* fused = (u16*)carve((size_t)2048 * 2112 * 2);   // [qa | ckv] per row
  u16* qan   = (u16*)carve((size_t)2048 * 1536 * 2);
  u16* q     = (u16*)carve((size_t)2048 * 6144 * 2);
  u16* cn    = (u16*)carve((size_t)2048 * 512 * 2);
  u16* qfb   = (u16*)carve((size_t)32 * 2048 * 192 * 2);
  u16* kfb   = (u16*)carve((size_t)32 * 2048 * 192 * 2);
  u16* vTb   = (u16*)carve((size_t)32 * 128 * 2048 * 2);
  u16* ob    = (u16*)carve((size_t)2048 * 4096 * 2);
  float* cost = (float*)carve((size_t)65536 * 4);
  float* sint = (float*)carve((size_t)65536 * 4);

  // --- prep: casts / transposes / tables ---
  cast_bf16_kernel<<<8192, 256, 0, stream>>>(hs, hs_bf, 2048 * 4096);
  transpose_cast_kernel<<<dim3(24, 64), 256, 0, stream>>>(Wqa, WabT, 4096, 1536);
  transpose_cast_kernel<<<dim3(9, 64), 256, 0, stream>>>(Wkva, WabT + (size_t)1536 * 4096, 4096, 576);
  transpose_cast_kernel<<<dim3(96, 24), 256, 0, stream>>>(Wqb, WqbT, 1536, 6144);
  transpose_cast_kernel<<<dim3(128, 8), 256, 0, stream>>>(Wkvb, WkvbT, 512, 8192);
  transpose_cast_kernel<<<dim3(64, 64), 256, 0, stream>>>(Wo, WoT, 4096, 4096);
  rope_table_kernel<<<256, 256, 0, stream>>>(cost, sint);

  // --- fused first-stage GEMM: [qa | ckv] = hs @ [Wqa | Wkva] ---
  gemm_v3_kernel<1><<<dim3(17, 16), 256, 0, stream>>>(hs_bf, WabT, fused, nullptr, 2048, 2112, 4096);

  // --- norms ---
  rmsnorm_kernel<<<2048, 256, 0, stream>>>(fused, qln, qan, 1536, 2112, 1536);
  rmsnorm_kernel<<<2048, 256, 0, stream>>>(fused + 1536, kvln, cn, 512, 2112, 512);

  // --- second-stage GEMMs; kv GEMM writes kf (nope) + vT directly ---
  gemm_v3_kernel<1><<<dim3(48, 16), 256, 0, stream>>>(qan, WqbT, q, nullptr, 2048, 6144, 1536);
  gemm_v3_kernel<2><<<dim3(64, 16), 256, 0, stream>>>(cn, WkvbT, kfb, vTb, 2048, 8192, 512);

  // --- head-major layouts + RoPE (vectorized) ---
  build_qf_kernel<<<6144, 256, 0, stream>>>(q, cost, sint, qfb);
  build_kf_rope_kernel<<<2048, 256, 0, stream>>>(fused + 1536, cost, sint, kfb);

  // --- attention (round-9: 512 blocks, 2/CU, head-pinned XCD, paired) ---
  mla_attn_kernel<<<dim3(32, 16), 256, 0, stream>>>(qfb, kfb, vTb, ob);

  // --- output projection ---
  gemm_v3_kernel<0><<<dim3(32, 16), 256, 0, stream>>>(ob, WoT, out, nullptr, 2048, 4096, 4096);
}

// Round 13
// 404.825 us; speedup vs baseline: 1.1565x; 1.0551x over previous
//
#include <hip/hip_runtime.h>

typedef unsigned short u16;
using bf16x8 = __attribute__((ext_vector_type(8))) __bf16;
using f32x4  = __attribute__((ext_vector_type(4))) float;
using s16x8  = __attribute__((ext_vector_type(8))) short;
using s16x4  = __attribute__((ext_vector_type(4))) short;

#define AS1 __attribute__((address_space(1)))
#define AS3 __attribute__((address_space(3)))

__device__ __forceinline__ void gload16(const u16* g, u16* l) {
  __builtin_amdgcn_global_load_lds((AS1 void*)(size_t)g, (AS3 void*)l, 16, 0, 0);
}

__device__ __forceinline__ u16 f2bf(float f) {
  unsigned u = __float_as_uint(f);
  u += 0x7fffu + ((u >> 16) & 1u);   // round-to-nearest-even
  return (u16)(u >> 16);
}
__device__ __forceinline__ float bf2f(u16 h) {
  return __uint_as_float(((unsigned)h) << 16);
}

// ================= merged prep: cast + 5 transposes + rope table =================
// 1-D grid, range-dispatched. Small transposes fill the machine concurrently.
__device__ __forceinline__ void transpose_tile(const float* __restrict__ W,
                                               u16* __restrict__ WT,
                                               int K, int N, int nb, int kb,
                                               u16 (*tile)[72]) {
  const int t = threadIdx.x;
  const int rr = t >> 3;        // 0..31
  const int cc = (t & 7) * 8;   // 0..56
#pragma unroll
  for (int pass = 0; pass < 2; ++pass) {
    const float* src = W + (size_t)(kb + pass * 32 + rr) * N + nb + cc;
    float4 a = *reinterpret_cast<const float4*>(src);
    float4 b = *reinterpret_cast<const float4*>(src + 4);
    u16* tr = &tile[pass * 32 + rr][cc];
    tr[0] = f2bf(a.x); tr[1] = f2bf(a.y); tr[2] = f2bf(a.z); tr[3] = f2bf(a.w);
    tr[4] = f2bf(b.x); tr[5] = f2bf(b.y); tr[6] = f2bf(b.z); tr[7] = f2bf(b.w);
  }
  __syncthreads();
#pragma unroll
  for (int pass = 0; pass < 2; ++pass) {
    s16x8 v;
#pragma unroll
    for (int j = 0; j < 8; ++j) v[j] = (short)tile[cc + j][pass * 32 + rr];
    *reinterpret_cast<s16x8*>(WT + (size_t)(nb + pass * 32 + rr) * K + kb + cc) = v;
  }
}

__global__ __launch_bounds__(256) void prep_merged_kernel(
    const float* __restrict__ hs, u16* __restrict__ hs_bf,
    const float* __restrict__ Wqa, const float* __restrict__ Wkva, u16* __restrict__ WabT,
    const float* __restrict__ Wqb, u16* __restrict__ WqbT,
    const float* __restrict__ Wkvb, u16* __restrict__ WkvbT,
    const float* __restrict__ Wo, u16* __restrict__ WoT,
    float* __restrict__ cost, float* __restrict__ sint) {
  __shared__ u16 tile[64][72];
  const int bid = blockIdx.x, t = threadIdx.x;
  if (bid < 8192) {                       // cast hs -> bf16
    int i = (bid * 256 + t) * 4;
    float4 v = *reinterpret_cast<const float4*>(hs + i);
    s16x4 o;
    o[0] = (short)f2bf(v.x); o[1] = (short)f2bf(v.y);
    o[2] = (short)f2bf(v.z); o[3] = (short)f2bf(v.w);
    *reinterpret_cast<s16x4*>(hs_bf + i) = o;
  } else if (bid < 9728) {                // Wqa [4096][1536] -> WabT[0..1536)
    int r = bid - 8192;
    transpose_tile(Wqa, WabT, 4096, 1536, (r % 24) * 64, (r / 24) * 64, tile);
  } else if (bid < 10304) {               // Wkva [4096][576] -> WabT[1536..2112)
    int r = bid - 9728;
    transpose_tile(Wkva, WabT + (size_t)1536 * 4096, 4096, 576, (r % 9) * 64, (r / 9) * 64, tile);
  } else if (bid < 12608) {               // Wqb [1536][6144]
    int r = bid - 10304;
    transpose_tile(Wqb, WqbT, 1536, 6144, (r % 96) * 64, (r / 96) * 64, tile);
  } else if (bid < 13632) {               // Wkvb [512][8192]
    int r = bid - 12608;
    transpose_tile(Wkvb, WkvbT, 512, 8192, (r % 128) * 64, (r / 128) * 64, tile);
  } else if (bid < 17728) {               // Wo [4096][4096]
    int r = bid - 13632;
    transpose_tile(Wo, WoT, 4096, 4096, (r % 64) * 64, (r / 64) * 64, tile);
  } else {                                // rope table
    int idx = (bid - 17728) * 256 + t;    // 65536
    int pos = idx >> 5, j = idx & 31;
    float inv = __expf(-(float)j * (9.210340371976184f / 32.0f));
    float f = (float)pos * inv;
    cost[idx] = cosf(f);
    sint[idx] = sinf(f);
  }
}

// ================= merged rmsnorms (q rows + kv rows in one launch) =================
__global__ __launch_bounds__(256) void norms_merged_kernel(const u16* __restrict__ fused,
                                                           const float* __restrict__ qln,
                                                           const float* __restrict__ kvln,
                                                           u16* __restrict__ qan,
                                                           u16* __restrict__ cn) {
  const int bid = blockIdx.x, t = threadIdx.x;
  const int row = bid & 2047;
  const bool is_q = bid < 2048;
  const int R = is_q ? 1536 : 512;
  const u16* xr = fused + (size_t)row * 2112 + (is_q ? 0 : 1536);
  const float* w = is_q ? qln : kvln;
  u16* yr = (is_q ? qan + (size_t)row * 1536 : cn + (size_t)row * 512);
  float ss = 0.f;
  for (int i = t; i < R; i += 256) { float f = bf2f(xr[i]); ss += f * f; }
#pragma unroll
  for (int m = 32; m >= 1; m >>= 1) ss += __shfl_xor(ss, m);
  __shared__ float red[4];
  if ((t & 63) == 0) red[t >> 6] = ss;
  __syncthreads();
  float tot = red[0] + red[1] + red[2] + red[3];
  float r = rsqrtf(tot / (float)R + 1e-6f);
  for (int i = t; i < R; i += 256) yr[i] = f2bf(bf2f(xr[i]) * r * w[i]);
}

// ================= merged builds: qf (RoPE+scale) + kf rope-only =================
__global__ __launch_bounds__(256) void builds_merged_kernel(const u16* __restrict__ q,
                                                            const u16* __restrict__ ckv,
                                                            const float* __restrict__ cost,
                                                            const float* __restrict__ sint,
                                                            u16* __restrict__ qf,
                                                            u16* __restrict__ kf) {
  const int bid = blockIdx.x, t = threadIdx.x;
  if (bid < 6144) {
    int o8 = (bid * 256 + t) * 8;
    const float scale = 0.07216878364870323f;  // 192^-0.5 folded into q
    int c = (o8 % 192) >> 3;
    int rest = o8 / 192;
    int s = rest & 2047, h = rest >> 11;
    const u16* qrow = q + ((size_t)s * 32 + h) * 192;
    s16x8 out;
    if (c < 16) {
      s16x8 v = *reinterpret_cast<const s16x8*>(qrow + c * 8);
#pragma unroll
      for (int j = 0; j < 8; ++j) out[j] = (short)f2bf(bf2f((u16)v[j]) * scale);
    } else {
      int j0 = c * 8 - 128;
      bool lo = j0 < 32;
      int jj0 = lo ? j0 : j0 - 32;
      s16x8 a = *reinterpret_cast<const s16x8*>(qrow + 128 + 2 * jj0);
      s16x8 b = *reinterpret_cast<const s16x8*>(qrow + 128 + 2 * jj0 + 8);
      float4 c0 = *reinterpret_cast<const float4*>(cost + s * 32 + jj0);
      float4 c1 = *reinterpret_cast<const float4*>(cost + s * 32 + jj0 + 4);
      float4 s0 = *reinterpret_cast<const float4*>(sint + s * 32 + jj0);
      float4 s1 = *reinterpret_cast<const float4*>(sint + s * 32 + jj0 + 4);
      float cs[8] = {c0.x, c0.y, c0.z, c0.w, c1.x, c1.y, c1.z, c1.w};
      float sn[8] = {s0.x, s0.y, s0.z, s0.w, s1.x, s1.y, s1.z, s1.w};
#pragma unroll
      for (int j = 0; j < 8; ++j) {
        float x0 = bf2f((u16)((j < 4) ? a[2 * j] : b[2 * j - 8]));
        float x1 = bf2f((u16)((j < 4) ? a[2 * j + 1] : b[2 * j - 7]));
        float v = lo ? (x0 * cs[j] - x1 * sn[j]) : (x1 * cs[j] + x0 * sn[j]);
        out[j] = (short)f2bf(v * scale);
      }
    }
    *reinterpret_cast<s16x8*>(qf + o8) = out;
  } else {
    int o8 = ((bid - 6144) * 256 + t) * 8;   // 32*2048*64 range
    int j0 = o8 & 63;
    int rest = o8 >> 6;
    int s = rest & 2047, h = rest >> 11;
    bool lo = j0 < 32;
    int jj0 = lo ? j0 : j0 - 32;
    const u16* crow = ckv + (size_t)s * 2112 + 512;
    s16x8 a = *reinterpret_cast<const s16x8*>(crow + 2 * jj0);
    s16x8 b = *reinterpret_cast<const s16x8*>(crow + 2 * jj0 + 8);
    float4 c0 = *reinterpret_cast<const float4*>(cost + s * 32 + jj0);
    float4 c1 = *reinterpret_cast<const float4*>(cost + s * 32 + jj0 + 4);
    float4 s0 = *reinterpret_cast<const float4*>(sint + s * 32 + jj0);
    float4 s1 = *reinterpret_cast<const float4*>(sint + s * 32 + jj0 + 4);
    float cs[8] = {c0.x, c0.y, c0.z, c0.w, c1.x, c1.y, c1.z, c1.w};
    float sn[8] = {s0.x, s0.y, s0.z, s0.w, s1.x, s1.y, s1.z, s1.w};
    s16x8 out;
#pragma unroll
    for (int j = 0; j < 8; ++j) {
      float x0 = bf2f((u16)((j < 4) ? a[2 * j] : b[2 * j - 8]));
      float x1 = bf2f((u16)((j < 4) ? a[2 * j + 1] : b[2 * j - 7]));
      float v = lo ? (x0 * cs[j] - x1 * sn[j]) : (x1 * cs[j] + x0 * sn[j]);
      out[j] = (short)f2bf(v);
    }
    *reinterpret_cast<s16x8*>(kf + ((size_t)h * 2048 + s) * 192 + 128 + j0) = out;
  }
}

// ---------------- GEMM v3 body: C[M][N] = A[M][K](bf16) * BT[N][K](bf16)^T ----------------
// 128x128 tile, BK=32, 4 waves (2x2). 4-deep LDS pipeline, prefetch distance 3,
// one raw s_barrier/iter with counted vmcnt(8), XOR-swizzled LDS, setprio MFMA.
// EPI: 0 = f32 C, 1 = bf16 C, 2 = MLA-kv split epilogue (kf nope + vT direct).
template <int EPI>
__device__ __forceinline__ void gemm_v3_body(const u16* __restrict__ A,
                                             const u16* __restrict__ BT,
                                             void* __restrict__ Cv,
                                             void* __restrict__ Cv2,
                                             int M, int N, int K,
                                             int bx, int by, u16* S) {
  const int t0 = threadIdx.x;
  const int lane = t0 & 63, wave = t0 >> 6;
  const int wr = wave >> 1, wc = wave & 1;
  const int row0 = by * 128, col0 = bx * 128;
  const int lrow = lane & 15, lkg = lane >> 4;

  const int lp = lane ^ ((lane >> 3) & 3);
  const int srow_off = lp >> 2;
  const int skel = (lp & 3) * 8;
  const int c0 = wave * 2, c1 = c0 + 1;
  const int arow_c0 = row0 + c0 * 16 + srow_off;
  const int arow_c1 = row0 + c1 * 16 + srow_off;
  int brow_c0 = col0 + c0 * 16 + srow_off; if (brow_c0 > N - 1) brow_c0 = N - 1;
  int brow_c1 = col0 + c1 * 16 + srow_off; if (brow_c1 > N - 1) brow_c1 = N - 1;

  int aoff[4], boff[4];
#pragma unroll
  for (int m = 0; m < 4; ++m) {
    int r = wr * 64 + m * 16 + lrow;
    int off = r * 32 + lkg * 8;
    aoff[m] = off ^ ((off >> 3) & 0x18);
    r = wc * 64 + m * 16 + lrow;
    off = r * 32 + lkg * 8;
    boff[m] = off ^ ((off >> 3) & 0x18);
  }

  const int NT = K >> 5;

#pragma unroll
  for (int pt = 0; pt < 3; ++pt) {
    u16* ab = &S[pt * 8192];
    const int kb = pt * 32 + skel;
    gload16(A  + (size_t)arow_c0 * K + kb, ab + c0 * 512);
    gload16(A  + (size_t)arow_c1 * K + kb, ab + c1 * 512);
    gload16(BT + (size_t)brow_c0 * K + kb, ab + 4096 + c0 * 512);
    gload16(BT + (size_t)brow_c1 * K + kb, ab + 4096 + c1 * 512);
  }

  f32x4 acc[4][4];
#pragma unroll
  for (int m = 0; m < 4; ++m)
#pragma unroll
    for (int n = 0; n < 4; ++n) acc[m][n] = 0.f;

  for (int t = 0; t < NT; ++t) {
    if (t + 2 < NT)      asm volatile("s_waitcnt vmcnt(8)" ::: "memory");
    else if (t + 1 < NT) asm volatile("s_waitcnt vmcnt(4)" ::: "memory");
    else                 asm volatile("s_waitcnt vmcnt(0)" ::: "memory");
    __builtin_amdgcn_s_barrier();
    __builtin_amdgcn_sched_barrier(0);

    const u16* ab = &S[(t & 3) * 8192];
    bf16x8 af[4], bb[4];
#pragma unroll
    for (int m = 0; m < 4; ++m)
      af[m] = *reinterpret_cast<const bf16x8*>(ab + aoff[m]);
#pragma unroll
    for (int n = 0; n < 4; ++n)
      bb[n] = *reinterpret_cast<const bf16x8*>(ab + 4096 + boff[n]);

    if (t + 3 < NT) {
      u16* sb = &S[((t + 3) & 3) * 8192];
      const int kb = (t + 3) * 32 + skel;
      gload16(A  + (size_t)arow_c0 * K + kb, sb + c0 * 512);
      gload16(A  + (size_t)arow_c1 * K + kb, sb + c1 * 512);
      gload16(BT + (size_t)brow_c0 * K + kb, sb + 4096 + c0 * 512);
      gload16(BT + (size_t)brow_c1 * K + kb, sb + 4096 + c1 * 512);
    }

    __builtin_amdgcn_s_setprio(1);
#pragma unroll
    for (int m = 0; m < 4; ++m)
#pragma unroll
      for (int n = 0; n < 4; ++n)
        acc[m][n] = __builtin_amdgcn_mfma_f32_16x16x32_bf16(af[m], bb[n], acc[m][n], 0, 0, 0);
    __builtin_amdgcn_s_setprio(0);
  }

#pragma unroll
  for (int m = 0; m < 4; ++m) {
#pragma unroll
    for (int n = 0; n < 4; ++n) {
      int col = col0 + wc * 64 + n * 16 + lrow;
      int row = row0 + wr * 64 + m * 16 + lkg * 4;
      if (EPI == 2) {
        // MLA kv split: col = h*256 + d. d<128 -> kf[h][row][d]; d>=128 -> vT[h][d-128][row..row+3]
        int d = col & 255, hh = col >> 8;
        if (d < 128) {
          u16* dst = (u16*)Cv + ((size_t)hh * 2048 + row) * 192 + d;
#pragma unroll
          for (int i = 0; i < 4; ++i) dst[(size_t)i * 192] = f2bf(acc[m][n][i]);
        } else {
          s16x4 v;
#pragma unroll
          for (int i = 0; i < 4; ++i) v[i] = (short)f2bf(acc[m][n][i]);
          *reinterpret_cast<s16x4*>((u16*)Cv2 + ((size_t)hh * 128 + (d - 128)) * 2048 + row) = v;
        }
      } else if (col < N) {
#pragma unroll
        for (int i = 0; i < 4; ++i) {
          size_t idx = (size_t)(row + i) * N + col;
          if (EPI == 1) ((u16*)Cv)[idx] = f2bf(acc[m][n][i]);
          else          ((float*)Cv)[idx] = acc[m][n][i];
        }
      }
    }
  }
}

template <int EPI>
__global__ __launch_bounds__(256) void gemm_v3_kernel(const u16* __restrict__ A,
                                                      const u16* __restrict__ BT,
                                                      void* __restrict__ Cv,
                                                      void* __restrict__ Cv2,
                                                      int M, int N, int K) {
  __shared__ __align__(16) u16 S[4 * 8192];
  gemm_v3_body<EPI>(A, BT, Cv, Cv2, M, N, K, blockIdx.x, blockIdx.y, S);
}

// merged q-GEMM (z=0) + kv-GEMM (z=1) launch: kv blocks backfill the q tail.
__global__ __launch_bounds__(256) void gemm_qkv_kernel(const u16* __restrict__ qan,
                                                       const u16* __restrict__ WqbT,
                                                       u16* __restrict__ qout,
                                                       const u16* __restrict__ cn,
                                                       const u16* __restrict__ WkvbT,
                                                       u16* __restrict__ kfb,
                                                       u16* __restrict__ vTb) {
  __shared__ __align__(16) u16 S[4 * 8192];
  if (blockIdx.z == 0) {
    if (blockIdx.x >= 48) return;
    gemm_v3_body<1>(qan, WqbT, qout, nullptr, 2048, 6144, 1536, blockIdx.x, blockIdx.y, S);
  } else {
    gemm_v3_body<2>(cn, WkvbT, kfb, vTb, 2048, 8192, 512, blockIdx.x, blockIdx.y, S);
  }
}

// ---------------- causal flash attention (round-9 structure: best known, ~129us) ----------------
// grid (h=32, pair=16): bid%8 = h%8 pins each head's K/V to one XCD L2.
// 512 blocks = 2/CU. Block handles qb=pair and qb=31-pair (33 KV-64 iters).
// 256 thr = 4 waves; wave w owns q rows qb*64+w*16..+16. K/V staged to LDS in
// fragment order via global_load_lds. T13 defer-max + deferred-l.
__global__ __launch_bounds__(256) void mla_attn_kernel(const u16* __restrict__ qf,
                                                       const u16* __restrict__ kf,
                                                       const u16* __restrict__ vT,
                                                       u16* __restrict__ o) {
  const int h = blockIdx.x, pair = blockIdx.y;
  const int t = threadIdx.x, wave = t >> 6, lane = t & 63;
  const int lrow = lane & 15, lkg = lane >> 4;
  __shared__ __align__(16) u16 Kt[24 * 512];
  __shared__ __align__(16) u16 Vt[16 * 512];
  __shared__ __align__(16) u16 Pl[4][16][72];

  const u16* ksrc0 = kf + ((size_t)h * 2048 + wave * 16 + lrow) * 192 + lkg * 8;
  const u16* vsrc0 = vT + ((size_t)h * 128 + wave * 32 + lrow) * 2048 + lkg * 8;

  for (int qq = 0; qq < 2; ++qq) {
    const int qb = qq ? (31 - pair) : pair;
    const int qbase = qb * 64 + wave * 16;

    bf16x8 qfr[6];
    const u16* qrow_ptr = qf + ((size_t)h * 2048 + qbase + lrow) * 192;
#pragma unroll
    for (int kk = 0; kk < 6; ++kk)
      qfr[kk] = *reinterpret_cast<const bf16x8*>(qrow_ptr + kk * 32 + lkg * 8);

    f32x4 acc_o[8];
#pragma unroll
    for (int f = 0; f < 8; ++f) acc_o[f] = 0.f;
    float m_run[4], l_par[4];
#pragma unroll
    for (int i = 0; i < 4; ++i) { m_run[i] = -1e30f; l_par[i] = 0.f; }

    const int kv_end = qb * 64 + 64;
    for (int kt = 0; kt < kv_end; kt += 64) {
      {
        const u16* ks = ksrc0 + (size_t)kt * 192;
#pragma unroll
        for (int kk = 0; kk < 6; ++kk)
          gload16(ks + kk * 32, &Kt[(wave * 6 + kk) * 512]);
#pragma unroll
        for (int j = 0; j < 4; ++j) {
          int fo = (j >> 1), ck = j & 1;
          gload16(vsrc0 + (size_t)fo * 16 * 2048 + kt + ck * 32,
                  &Vt[((wave * 2 + fo) * 2 + ck) * 512]);
        }
      }
      __syncthreads();

      f32x4 sv[4];
#pragma unroll
      for (int cg = 0; cg < 4; ++cg) sv[cg] = 0.f;
#pragma unroll
      for (int cg = 0; cg < 4; ++cg)
#pragma unroll
        for (int kk = 0; kk < 6; ++kk) {
          bf16x8 kfr = *reinterpret_cast<const bf16x8*>(&Kt[(cg * 6 + kk) * 512 + lane * 8]);
          sv[cg] = __builtin_amdgcn_mfma_f32_16x16x32_bf16(qfr[kk], kfr, sv[cg], 0, 0, 0);
        }

      const int qrow_b = qbase + lkg * 4;
      if (kt + 64 >= kv_end) {
#pragma unroll
        for (int cg = 0; cg < 4; ++cg) {
          int kvcol = kt + cg * 16 + lrow;
#pragma unroll
          for (int i = 0; i < 4; ++i)
            if (kvcol > qrow_b + i) sv[cg][i] = -__builtin_inff();
        }
      }
      float tmax[4];
#pragma unroll
      for (int i = 0; i < 4; ++i)
        tmax[i] = fmaxf(fmaxf(sv[0][i], sv[1][i]), fmaxf(sv[2][i], sv[3][i]));
#pragma unroll
      for (int m = 8; m >= 1; m >>= 1)
#pragma unroll
        for (int i = 0; i < 4; ++i) tmax[i] = fmaxf(tmax[i], __shfl_xor(tmax[i], m));
      int need = 0;
#pragma unroll
      for (int i = 0; i < 4; ++i) need |= (tmax[i] > m_run[i] + 8.f) ? 1 : 0;
      if (__any(need)) {
#pragma unroll
        for (int i = 0; i < 4; ++i) {
          float mnew = fmaxf(m_run[i], tmax[i]);
          float alpha = __expf(m_run[i] - mnew);
          m_run[i] = mnew;
          l_par[i] *= alpha;
#pragma unroll
          for (int f = 0; f < 8; ++f) acc_o[f][i] *= alpha;
        }
      }
#pragma unroll
      for (int i = 0; i < 4; ++i) {
#pragma unroll
        for (int cg = 0; cg < 4; ++cg) sv[cg][i] = __expf(sv[cg][i] - m_run[i]);
        l_par[i] += (sv[0][i] + sv[1][i]) + (sv[2][i] + sv[3][i]);
      }
#pragma unroll
      for (int cg = 0; cg < 4; ++cg)
#pragma unroll
        for (int i = 0; i < 4; ++i)
          Pl[wave][lkg * 4 + i][cg * 16 + lrow] = f2bf(sv[cg][i]);
#pragma unroll
      for (int ck = 0; ck < 2; ++ck) {
        bf16x8 pf = *reinterpret_cast<const bf16x8*>(&Pl[wave][lrow][ck * 32 + lkg * 8]);
#pragma unroll
        for (int f = 0; f < 8; ++f) {
          bf16x8 vfr = *reinterpret_cast<const bf16x8*>(&Vt[(f * 2 + ck) * 512 + lane * 8]);
          acc_o[f] = __builtin_amdgcn_mfma_f32_16x16x32_bf16(pf, vfr, acc_o[f], 0, 0, 0);
        }
      }
      __syncthreads();
    }
#pragma unroll
    for (int i = 0; i < 4; ++i)
#pragma unroll
      for (int m = 8; m >= 1; m >>= 1) l_par[i] += __shfl_xor(l_par[i], m);
#pragma unroll
    for (int f = 0; f < 8; ++f)
#pragma unroll
      for (int i = 0; i < 4; ++i) {
        int row = qbase + lkg * 4 + i;
        int col = h * 128 + f * 16 + lrow;
        o[(size_t)row * 4096 + col] = f2bf(acc_o[f][i] / l_par[i]);
      }
  }
}

// ---------------------------------------------------------------
extern "C" void kernel_launch(void* const* d_in, const int* in_sizes, int n_in,
                              void* d_out, int out_size, void* d_ws, size_t ws_size,
                              hipStream_t stream) {
  (void)in_sizes; (void)n_in; (void)out_size; (void)ws_size;
  const float* hs   = (const float*)d_in[0];
  const float* Wqa  = (const float*)d_in[1];
  const float* qln  = (const float*)d_in[2];
  const float* Wqb  = (const float*)d_in[3];
  const float* Wkva = (const float*)d_in[4];
  const float* kvln = (const float*)d_in[5];
  const float* Wkvb = (const float*)d_in[6];
  const float* Wo   = (const float*)d_in[7];
  float* out = (float*)d_out;

  char* p = (char*)d_ws;
  size_t off = 0;
  auto carve = [&](size_t bytes) {
    char* r = p + off;
    off += (bytes + 255) & ~(size_t)255;
    return r;
  };
  u16* hs_bf = (u16*)carve((size_t)2048 * 4096 * 2);
  u16* WabT  = (u16*)carve((size_t)2112 * 4096 * 2);   // [0..1535]=WqaT, [1536..2111]=WkvaT
  u16* WqbT  = (u16*)carve((size_t)6144 * 1536 * 2);
  u16* WkvbT = (u16*)carve((size_t)8192 * 512 * 2);
  u16* WoT   = (u16*)carve((size_t)4096 * 4096 * 2);
  u16* fused = (u16*)carve((size_t)2048 * 2112 * 2);   // [qa | ckv] per row
  u16* qan   = (u16*)carve((size_t)2048 * 1536 * 2);
  u16* q     = (u16*)carve((size_t)2048 * 6144 * 2);
  u16* cn    = (u16*)carve((size_t)2048 * 512 * 2);
  u16* qfb   = (u16*)carve((size_t)32 * 2048 * 192 * 2);
  u16* kfb   = (u16*)carve((size_t)32 * 2048 * 192 * 2);
  u16* vTb   = (u16*)carve((size_t)32 * 128 * 2048 * 2);
  u16* ob    = (u16*)carve((size_t)2048 * 4096 * 2);
  float* cost = (float*)carve((size_t)65536 * 4);
  float* sint = (float*)carve((size_t)65536 * 4);

  // --- merged prep: cast + 5 transposes + rope table (1 launch) ---
  prep_merged_kernel<<<17984, 256, 0, stream>>>(hs, hs_bf, Wqa, Wkva, WabT,
                                                Wqb, WqbT, Wkvb, WkvbT, Wo, WoT,
                                                cost, sint);

  // --- fused first-stage GEMM: [qa | ckv] = hs @ [Wqa | Wkva] ---
  gemm_v3_kernel<1><<<dim3(17, 16), 256, 0, stream>>>(hs_bf, WabT, fused, nullptr, 2048, 2112, 4096);

  // --- merged norms (1 launch) ---
  norms_merged_kernel<<<4096, 256, 0, stream>>>(fused, qln, kvln, qan, cn);

  // --- merged q+kv second-stage GEMMs (1 launch; kv backfills q tail) ---
  gemm_qkv_kernel<<<dim3(64, 16, 2), 256, 0, stream>>>(qan, WqbT, q, cn, WkvbT, kfb, vTb);

  // --- merged builds: qf RoPE+scale, kf RoPE (1 launch) ---
  builds_merged_kernel<<<8192, 256, 0, stream>>>(q, fused + 1536, cost, sint, qfb, kfb);

  // --- attention (round-9: 512 blocks, 2/CU, head-pinned XCD, paired) ---
  mla_attn_kernel<<<dim3(32, 16), 256, 0, stream>>>(qfb, kfb, vTb, ob);

  // --- output projection ---
  gemm_v3_kernel<0><<<dim3(32, 16), 256, 0, stream>>>(ob, WoT, out, nullptr, 2048, 4096, 4096);
}

// Round 14
// 403.105 us; speedup vs baseline: 1.1615x; 1.0043x over previous
//
#include <hip/hip_runtime.h>

typedef unsigned short u16;
using bf16x8 = __attribute__((ext_vector_type(8))) __bf16;
using f32x4  = __attribute__((ext_vector_type(4))) float;
using s16x8  = __attribute__((ext_vector_type(8))) short;
using s16x4  = __attribute__((ext_vector_type(4))) short;

#define AS1 __attribute__((address_space(1)))
#define AS3 __attribute__((address_space(3)))

__device__ __forceinline__ void gload16(const u16* g, u16* l) {
  __builtin_amdgcn_global_load_lds((AS1 void*)(size_t)g, (AS3 void*)l, 16, 0, 0);
}

__device__ __forceinline__ u16 f2bf(float f) {
  unsigned u = __float_as_uint(f);
  u += 0x7fffu + ((u >> 16) & 1u);   // round-to-nearest-even
  return (u16)(u >> 16);
}
__device__ __forceinline__ float bf2f(u16 h) {
  return __uint_as_float(((unsigned)h) << 16);
}

// ================= merged prep: cast + 5 transposes + rope table =================
__device__ __forceinline__ void transpose_tile(const float* __restrict__ W,
                                               u16* __restrict__ WT,
                                               int K, int N, int nb, int kb,
                                               u16 (*tile)[72]) {
  const int t = threadIdx.x;
  const int rr = t >> 3;        // 0..31
  const int cc = (t & 7) * 8;   // 0..56
#pragma unroll
  for (int pass = 0; pass < 2; ++pass) {
    const float* src = W + (size_t)(kb + pass * 32 + rr) * N + nb + cc;
    float4 a = *reinterpret_cast<const float4*>(src);
    float4 b = *reinterpret_cast<const float4*>(src + 4);
    u16* tr = &tile[pass * 32 + rr][cc];
    tr[0] = f2bf(a.x); tr[1] = f2bf(a.y); tr[2] = f2bf(a.z); tr[3] = f2bf(a.w);
    tr[4] = f2bf(b.x); tr[5] = f2bf(b.y); tr[6] = f2bf(b.z); tr[7] = f2bf(b.w);
  }
  __syncthreads();
#pragma unroll
  for (int pass = 0; pass < 2; ++pass) {
    s16x8 v;
#pragma unroll
    for (int j = 0; j < 8; ++j) v[j] = (short)tile[cc + j][pass * 32 + rr];
    *reinterpret_cast<s16x8*>(WT + (size_t)(nb + pass * 32 + rr) * K + kb + cc) = v;
  }
}

__global__ __launch_bounds__(256) void prep_merged_kernel(
    const float* __restrict__ hs, u16* __restrict__ hs_bf,
    const float* __restrict__ Wqa, const float* __restrict__ Wkva, u16* __restrict__ WabT,
    const float* __restrict__ Wqb, u16* __restrict__ WqbT,
    const float* __restrict__ Wkvb, u16* __restrict__ WkvbT,
    const float* __restrict__ Wo, u16* __restrict__ WoT,
    float* __restrict__ cost, float* __restrict__ sint) {
  __shared__ u16 tile[64][72];
  const int bid = blockIdx.x, t = threadIdx.x;
  if (bid < 8192) {                       // cast hs -> bf16
    int i = (bid * 256 + t) * 4;
    float4 v = *reinterpret_cast<const float4*>(hs + i);
    s16x4 o;
    o[0] = (short)f2bf(v.x); o[1] = (short)f2bf(v.y);
    o[2] = (short)f2bf(v.z); o[3] = (short)f2bf(v.w);
    *reinterpret_cast<s16x4*>(hs_bf + i) = o;
  } else if (bid < 9728) {                // Wqa [4096][1536] -> WabT[0..1536)
    int r = bid - 8192;
    transpose_tile(Wqa, WabT, 4096, 1536, (r % 24) * 64, (r / 24) * 64, tile);
  } else if (bid < 10304) {               // Wkva [4096][576] -> WabT[1536..2112)
    int r = bid - 9728;
    transpose_tile(Wkva, WabT + (size_t)1536 * 4096, 4096, 576, (r % 9) * 64, (r / 9) * 64, tile);
  } else if (bid < 12608) {               // Wqb [1536][6144]
    int r = bid - 10304;
    transpose_tile(Wqb, WqbT, 1536, 6144, (r % 96) * 64, (r / 96) * 64, tile);
  } else if (bid < 13632) {               // Wkvb [512][8192]
    int r = bid - 12608;
    transpose_tile(Wkvb, WkvbT, 512, 8192, (r % 128) * 64, (r / 128) * 64, tile);
  } else if (bid < 17728) {               // Wo [4096][4096]
    int r = bid - 13632;
    transpose_tile(Wo, WoT, 4096, 4096, (r % 64) * 64, (r / 64) * 64, tile);
  } else {                                // rope table
    int idx = (bid - 17728) * 256 + t;    // 65536
    int pos = idx >> 5, j = idx & 31;
    float inv = __expf(-(float)j * (9.210340371976184f / 32.0f));
    float f = (float)pos * inv;
    cost[idx] = cosf(f);
    sint[idx] = sinf(f);
  }
}

// ================= merged rmsnorms =================
__global__ __launch_bounds__(256) void norms_merged_kernel(const u16* __restrict__ fused,
                                                           const float* __restrict__ qln,
                                                           const float* __restrict__ kvln,
                                                           u16* __restrict__ qan,
                                                           u16* __restrict__ cn) {
  const int bid = blockIdx.x, t = threadIdx.x;
  const int row = bid & 2047;
  const bool is_q = bid < 2048;
  const int R = is_q ? 1536 : 512;
  const u16* xr = fused + (size_t)row * 2112 + (is_q ? 0 : 1536);
  const float* w = is_q ? qln : kvln;
  u16* yr = (is_q ? qan + (size_t)row * 1536 : cn + (size_t)row * 512);
  float ss = 0.f;
  for (int i = t; i < R; i += 256) { float f = bf2f(xr[i]); ss += f * f; }
#pragma unroll
  for (int m = 32; m >= 1; m >>= 1) ss += __shfl_xor(ss, m);
  __shared__ float red[4];
  if ((t & 63) == 0) red[t >> 6] = ss;
  __syncthreads();
  float tot = red[0] + red[1] + red[2] + red[3];
  float r = rsqrtf(tot / (float)R + 1e-6f);
  for (int i = t; i < R; i += 256) yr[i] = f2bf(bf2f(xr[i]) * r * w[i]);
}

// ================= merged builds: qf (RoPE+scale) + kf rope-only =================
__global__ __launch_bounds__(256) void builds_merged_kernel(const u16* __restrict__ q,
                                                            const u16* __restrict__ ckv,
                                                            const float* __restrict__ cost,
                                                            const float* __restrict__ sint,
                                                            u16* __restrict__ qf,
                                                            u16* __restrict__ kf) {
  const int bid = blockIdx.x, t = threadIdx.x;
  if (bid < 6144) {
    int o8 = (bid * 256 + t) * 8;
    const float scale = 0.07216878364870323f;  // 192^-0.5 folded into q
    int c = (o8 % 192) >> 3;
    int rest = o8 / 192;
    int s = rest & 2047, h = rest >> 11;
    const u16* qrow = q + ((size_t)s * 32 + h) * 192;
    s16x8 out;
    if (c < 16) {
      s16x8 v = *reinterpret_cast<const s16x8*>(qrow + c * 8);
#pragma unroll
      for (int j = 0; j < 8; ++j) out[j] = (short)f2bf(bf2f((u16)v[j]) * scale);
    } else {
      int j0 = c * 8 - 128;
      bool lo = j0 < 32;
      int jj0 = lo ? j0 : j0 - 32;
      s16x8 a = *reinterpret_cast<const s16x8*>(qrow + 128 + 2 * jj0);
      s16x8 b = *reinterpret_cast<const s16x8*>(qrow + 128 + 2 * jj0 + 8);
      float4 c0 = *reinterpret_cast<const float4*>(cost + s * 32 + jj0);
      float4 c1 = *reinterpret_cast<const float4*>(cost + s * 32 + jj0 + 4);
      float4 s0 = *reinterpret_cast<const float4*>(sint + s * 32 + jj0);
      float4 s1 = *reinterpret_cast<const float4*>(sint + s * 32 + jj0 + 4);
      float cs[8] = {c0.x, c0.y, c0.z, c0.w, c1.x, c1.y, c1.z, c1.w};
      float sn[8] = {s0.x, s0.y, s0.z, s0.w, s1.x, s1.y, s1.z, s1.w};
#pragma unroll
      for (int j = 0; j < 8; ++j) {
        float x0 = bf2f((u16)((j < 4) ? a[2 * j] : b[2 * j - 8]));
        float x1 = bf2f((u16)((j < 4) ? a[2 * j + 1] : b[2 * j - 7]));
        float v = lo ? (x0 * cs[j] - x1 * sn[j]) : (x1 * cs[j] + x0 * sn[j]);
        out[j] = (short)f2bf(v * scale);
      }
    }
    *reinterpret_cast<s16x8*>(qf + o8) = out;
  } else {
    int o8 = ((bid - 6144) * 256 + t) * 8;   // 32*2048*64 range
    int j0 = o8 & 63;
    int rest = o8 >> 6;
    int s = rest & 2047, h = rest >> 11;
    bool lo = j0 < 32;
    int jj0 = lo ? j0 : j0 - 32;
    const u16* crow = ckv + (size_t)s * 2112 + 512;
    s16x8 a = *reinterpret_cast<const s16x8*>(crow + 2 * jj0);
    s16x8 b = *reinterpret_cast<const s16x8*>(crow + 2 * jj0 + 8);
    float4 c0 = *reinterpret_cast<const float4*>(cost + s * 32 + jj0);
    float4 c1 = *reinterpret_cast<const float4*>(cost + s * 32 + jj0 + 4);
    float4 s0 = *reinterpret_cast<const float4*>(sint + s * 32 + jj0);
    float4 s1 = *reinterpret_cast<const float4*>(sint + s * 32 + jj0 + 4);
    float cs[8] = {c0.x, c0.y, c0.z, c0.w, c1.x, c1.y, c1.z, c1.w};
    float sn[8] = {s0.x, s0.y, s0.z, s0.w, s1.x, s1.y, s1.z, s1.w};
    s16x8 out;
#pragma unroll
    for (int j = 0; j < 8; ++j) {
      float x0 = bf2f((u16)((j < 4) ? a[2 * j] : b[2 * j - 8]));
      float x1 = bf2f((u16)((j < 4) ? a[2 * j + 1] : b[2 * j - 7]));
      float v = lo ? (x0 * cs[j] - x1 * sn[j]) : (x1 * cs[j] + x0 * sn[j]);
      out[j] = (short)f2bf(v);
    }
    *reinterpret_cast<s16x8*>(kf + ((size_t)h * 2048 + s) * 192 + 128 + j0) = out;
  }
}

// ---------------- GEMM v3 body ----------------
template <int EPI>
__device__ __forceinline__ void gemm_v3_body(const u16* __restrict__ A,
                                             const u16* __restrict__ BT,
                                             void* __restrict__ Cv,
                                             void* __restrict__ Cv2,
                                             int M, int N, int K,
                                             int bx, int by, u16* S) {
  const int t0 = threadIdx.x;
  const int lane = t0 & 63, wave = t0 >> 6;
  const int wr = wave >> 1, wc = wave & 1;
  const int row0 = by * 128, col0 = bx * 128;
  const int lrow = lane & 15, lkg = lane >> 4;

  const int lp = lane ^ ((lane >> 3) & 3);
  const int srow_off = lp >> 2;
  const int skel = (lp & 3) * 8;
  const int c0 = wave * 2, c1 = c0 + 1;
  const int arow_c0 = row0 + c0 * 16 + srow_off;
  const int arow_c1 = row0 + c1 * 16 + srow_off;
  int brow_c0 = col0 + c0 * 16 + srow_off; if (brow_c0 > N - 1) brow_c0 = N - 1;
  int brow_c1 = col0 + c1 * 16 + srow_off; if (brow_c1 > N - 1) brow_c1 = N - 1;

  int aoff[4], boff[4];
#pragma unroll
  for (int m = 0; m < 4; ++m) {
    int r = wr * 64 + m * 16 + lrow;
    int off = r * 32 + lkg * 8;
    aoff[m] = off ^ ((off >> 3) & 0x18);
    r = wc * 64 + m * 16 + lrow;
    off = r * 32 + lkg * 8;
    boff[m] = off ^ ((off >> 3) & 0x18);
  }

  const int NT = K >> 5;

#pragma unroll
  for (int pt = 0; pt < 3; ++pt) {
    u16* ab = &S[pt * 8192];
    const int kb = pt * 32 + skel;
    gload16(A  + (size_t)arow_c0 * K + kb, ab + c0 * 512);
    gload16(A  + (size_t)arow_c1 * K + kb, ab + c1 * 512);
    gload16(BT + (size_t)brow_c0 * K + kb, ab + 4096 + c0 * 512);
    gload16(BT + (size_t)brow_c1 * K + kb, ab + 4096 + c1 * 512);
  }

  f32x4 acc[4][4];
#pragma unroll
  for (int m = 0; m < 4; ++m)
#pragma unroll
    for (int n = 0; n < 4; ++n) acc[m][n] = 0.f;

  for (int t = 0; t < NT; ++t) {
    if (t + 2 < NT)      asm volatile("s_waitcnt vmcnt(8)" ::: "memory");
    else if (t + 1 < NT) asm volatile("s_waitcnt vmcnt(4)" ::: "memory");
    else                 asm volatile("s_waitcnt vmcnt(0)" ::: "memory");
    __builtin_amdgcn_s_barrier();
    __builtin_amdgcn_sched_barrier(0);

    const u16* ab = &S[(t & 3) * 8192];
    bf16x8 af[4], bb[4];
#pragma unroll
    for (int m = 0; m < 4; ++m)
      af[m] = *reinterpret_cast<const bf16x8*>(ab + aoff[m]);
#pragma unroll
    for (int n = 0; n < 4; ++n)
      bb[n] = *reinterpret_cast<const bf16x8*>(ab + 4096 + boff[n]);

    if (t + 3 < NT) {
      u16* sb = &S[((t + 3) & 3) * 8192];
      const int kb = (t + 3) * 32 + skel;
      gload16(A  + (size_t)arow_c0 * K + kb, sb + c0 * 512);
      gload16(A  + (size_t)arow_c1 * K + kb, sb + c1 * 512);
      gload16(BT + (size_t)brow_c0 * K + kb, sb + 4096 + c0 * 512);
      gload16(BT + (size_t)brow_c1 * K + kb, sb + 4096 + c1 * 512);
    }

    __builtin_amdgcn_s_setprio(1);
#pragma unroll
    for (int m = 0; m < 4; ++m)
#pragma unroll
      for (int n = 0; n < 4; ++n)
        acc[m][n] = __builtin_amdgcn_mfma_f32_16x16x32_bf16(af[m], bb[n], acc[m][n], 0, 0, 0);
    __builtin_amdgcn_s_setprio(0);
  }

#pragma unroll
  for (int m = 0; m < 4; ++m) {
#pragma unroll
    for (int n = 0; n < 4; ++n) {
      int col = col0 + wc * 64 + n * 16 + lrow;
      int row = row0 + wr * 64 + m * 16 + lkg * 4;
      if (EPI == 2) {
        int d = col & 255, hh = col >> 8;
        if (d < 128) {
          u16* dst = (u16*)Cv + ((size_t)hh * 2048 + row) * 192 + d;
#pragma unroll
          for (int i = 0; i < 4; ++i) dst[(size_t)i * 192] = f2bf(acc[m][n][i]);
        } else {
          s16x4 v;
#pragma unroll
          for (int i = 0; i < 4; ++i) v[i] = (short)f2bf(acc[m][n][i]);
          *reinterpret_cast<s16x4*>((u16*)Cv2 + ((size_t)hh * 128 + (d - 128)) * 2048 + row) = v;
        }
      } else if (col < N) {
#pragma unroll
        for (int i = 0; i < 4; ++i) {
          size_t idx = (size_t)(row + i) * N + col;
          if (EPI == 1) ((u16*)Cv)[idx] = f2bf(acc[m][n][i]);
          else          ((float*)Cv)[idx] = acc[m][n][i];
        }
      }
    }
  }
}

template <int EPI>
__global__ __launch_bounds__(256) void gemm_v3_kernel(const u16* __restrict__ A,
                                                      const u16* __restrict__ BT,
                                                      void* __restrict__ Cv,
                                                      void* __restrict__ Cv2,
                                                      int M, int N, int K) {
  __shared__ __align__(16) u16 S[4 * 8192];
  gemm_v3_body<EPI>(A, BT, Cv, Cv2, M, N, K, blockIdx.x, blockIdx.y, S);
}

__global__ __launch_bounds__(256) void gemm_qkv_kernel(const u16* __restrict__ qan,
                                                       const u16* __restrict__ WqbT,
                                                       u16* __restrict__ qout,
                                                       const u16* __restrict__ cn,
                                                       const u16* __restrict__ WkvbT,
                                                       u16* __restrict__ kfb,
                                                       u16* __restrict__ vTb) {
  __shared__ __align__(16) u16 S[4 * 8192];
  if (blockIdx.z == 0) {
    if (blockIdx.x >= 48) return;
    gemm_v3_body<1>(qan, WqbT, qout, nullptr, 2048, 6144, 1536, blockIdx.x, blockIdx.y, S);
  } else {
    gemm_v3_body<2>(cn, WkvbT, kfb, vTb, 2048, 8192, 512, blockIdx.x, blockIdx.y, S);
  }
}

// ---------------- causal flash attention v6: KVBLK=32, full K/V dbuf, counted vmcnt ----------------
// grid (h=32, pair=16): bid%8 = h%8 pins each head's K/V to one XCD L2. 512 blocks
// = 2/CU (LDS 45.5KB <= 80KB). Block handles qb=pair and 31-pair. 4 waves x 16 rows.
// Per iter: each wave stages 5 chunks (3 K + 2 V) of tile t+1, vmcnt(5) retires
// tile t's loads (>=5 older than newest 5) while t+1 flies across the raw barrier
// (T4). All waves pass vmcnt(5) before the barrier -> block-wide tile-t visibility.
// T13 defer-max + deferred-l. Wave-uniform skip of fully-masked half-tiles.
__global__ __launch_bounds__(256) void mla_attn_kernel(const u16* __restrict__ qf,
                                                       const u16* __restrict__ kf,
                                                       const u16* __restrict__ vT,
                                                       u16* __restrict__ o) {
  const int h = blockIdx.x, pair = blockIdx.y;
  const int t = threadIdx.x, wave = t >> 6, lane = t & 63;
  const int lrow = lane & 15, lkg = lane >> 4;
  __shared__ __align__(16) u16 Kt[2][12 * 512];   // chunk c=cg*6+kk: K[cg*16+l&15][kk*32+(l>>4)*8]
  __shared__ __align__(16) u16 Vt[2][8 * 512];    // chunk f: vT[f*16+l&15][(l>>4)*8]
  __shared__ __align__(16) u16 Pl[4][16][36];

  // staging sources: wave w stages K chunks 3w..3w+2, V chunks 2w..2w+1
  const u16* ksrc[3]; u16 *kdst0[3], *kdst1[3];
#pragma unroll
  for (int i = 0; i < 3; ++i) {
    int c = wave * 3 + i, cg = c / 6, kk = c - cg * 6;
    ksrc[i] = kf + ((size_t)h * 2048 + cg * 16 + lrow) * 192 + kk * 32 + lkg * 8;
    kdst0[i] = &Kt[0][c * 512];
    kdst1[i] = &Kt[1][c * 512];
  }
  const u16* vsrc[2]; u16 *vdst0[2], *vdst1[2];
#pragma unroll
  for (int j = 0; j < 2; ++j) {
    int f = wave * 2 + j;
    vsrc[j] = vT + ((size_t)h * 128 + f * 16 + lrow) * 2048 + lkg * 8;
    vdst0[j] = &Vt[0][f * 512];
    vdst1[j] = &Vt[1][f * 512];
  }

  for (int qq = 0; qq < 2; ++qq) {
    const int qb = qq ? (31 - pair) : pair;
    const int qbase = qb * 64 + wave * 16;

    bf16x8 qfr[6];
    const u16* qrow_ptr = qf + ((size_t)h * 2048 + qbase + lrow) * 192;
#pragma unroll
    for (int kk = 0; kk < 6; ++kk)
      qfr[kk] = *reinterpret_cast<const bf16x8*>(qrow_ptr + kk * 32 + lkg * 8);

    f32x4 acc_o[8];
#pragma unroll
    for (int f = 0; f < 8; ++f) acc_o[f] = 0.f;
    float m_run[4], l_par[4];
#pragma unroll
    for (int i = 0; i < 4; ++i) { m_run[i] = -1e30f; l_par[i] = 0.f; }

    const int nt = 2 * qb + 2;   // KV tiles of 32

    // prologue: stage tile 0 into buf 0
#pragma unroll
    for (int i = 0; i < 3; ++i) gload16(ksrc[i], kdst0[i]);
#pragma unroll
    for (int j = 0; j < 2; ++j) gload16(vsrc[j], vdst0[j]);

    for (int it = 0; it < nt; ++it) {
      const int kt = it * 32;
      if (it + 1 < nt) {   // prefetch tile it+1 into other buffer
        const int nb = (it + 1) & 1;
        const size_t kadv = (size_t)(it + 1) * 32 * 192;
        const size_t vadv = (size_t)(it + 1) * 32;
#pragma unroll
        for (int i = 0; i < 3; ++i) gload16(ksrc[i] + kadv, nb ? kdst1[i] : kdst0[i]);
#pragma unroll
        for (int j = 0; j < 2; ++j) gload16(vsrc[j] + vadv, nb ? vdst1[j] : vdst0[j]);
        asm volatile("s_waitcnt vmcnt(5)" ::: "memory");
      } else {
        asm volatile("s_waitcnt vmcnt(0)" ::: "memory");
      }
      __builtin_amdgcn_s_barrier();
      __builtin_amdgcn_sched_barrier(0);

      const u16* Kb = &Kt[it & 1][0];
      const u16* Vb = &Vt[it & 1][0];
      if (kt <= qbase + 15) {   // wave-uniform: skip fully-masked half-tiles
        // ---- S = Q K^T (16 x 32) ----
        f32x4 sv[2];
        sv[0] = 0.f; sv[1] = 0.f;
#pragma unroll
        for (int cg = 0; cg < 2; ++cg)
#pragma unroll
          for (int kk = 0; kk < 6; ++kk) {
            bf16x8 kfr = *reinterpret_cast<const bf16x8*>(&Kb[(cg * 6 + kk) * 512 + lane * 8]);
            sv[cg] = __builtin_amdgcn_mfma_f32_16x16x32_bf16(qfr[kk], kfr, sv[cg], 0, 0, 0);
          }
        // ---- causal mask (diagonal region only) ----
        const int qrow_b = qbase + lkg * 4;
        if (kt + 31 > qbase) {
#pragma unroll
          for (int cg = 0; cg < 2; ++cg) {
            int kvcol = kt + cg * 16 + lrow;
#pragma unroll
            for (int i = 0; i < 4; ++i)
              if (kvcol > qrow_b + i) sv[cg][i] = -__builtin_inff();
          }
        }
        // ---- softmax: defer-max + deferred-l ----
        float tmax[4];
#pragma unroll
        for (int i = 0; i < 4; ++i) tmax[i] = fmaxf(sv[0][i], sv[1][i]);
#pragma unroll
        for (int m = 8; m >= 1; m >>= 1)
#pragma unroll
          for (int i = 0; i < 4; ++i) tmax[i] = fmaxf(tmax[i], __shfl_xor(tmax[i], m));
        int need = 0;
#pragma unroll
        for (int i = 0; i < 4; ++i) need |= (tmax[i] > m_run[i] + 8.f) ? 1 : 0;
        if (__any(need)) {
#pragma unroll
          for (int i = 0; i < 4; ++i) {
            float mnew = fmaxf(m_run[i], tmax[i]);
            float alpha = __expf(m_run[i] - mnew);
            m_run[i] = mnew;
            l_par[i] *= alpha;
#pragma unroll
            for (int f = 0; f < 8; ++f) acc_o[f][i] *= alpha;
          }
        }
#pragma unroll
        for (int i = 0; i < 4; ++i) {
          sv[0][i] = __expf(sv[0][i] - m_run[i]);
          sv[1][i] = __expf(sv[1][i] - m_run[i]);
          l_par[i] += sv[0][i] + sv[1][i];
        }
        // ---- P -> bf16 -> per-wave LDS ----
#pragma unroll
        for (int cg = 0; cg < 2; ++cg)
#pragma unroll
          for (int i = 0; i < 4; ++i)
            Pl[wave][lkg * 4 + i][cg * 16 + lrow] = f2bf(sv[cg][i]);
        // ---- O += P V (1 P read feeds 8 MFMAs) ----
        bf16x8 pf = *reinterpret_cast<const bf16x8*>(&Pl[wave][lrow][lkg * 8]);
#pragma unroll
        for (int f = 0; f < 8; ++f) {
          bf16x8 vfr = *reinterpret_cast<const bf16x8*>(&Vb[f * 512 + lane * 8]);
          acc_o[f] = __builtin_amdgcn_mfma_f32_16x16x32_bf16(pf, vfr, acc_o[f], 0, 0, 0);
        }
      }
      __builtin_amdgcn_sched_barrier(0);
      __builtin_amdgcn_s_barrier();   // all waves done reading this buf before restage
    }
    // ---- epilogue: one l reduce, divide, store ----
#pragma unroll
    for (int i = 0; i < 4; ++i)
#pragma unroll
      for (int m = 8; m >= 1; m >>= 1) l_par[i] += __shfl_xor(l_par[i], m);
#pragma unroll
    for (int f = 0; f < 8; ++f)
#pragma unroll
      for (int i = 0; i < 4; ++i) {
        int row = qbase + lkg * 4 + i;
        int col = h * 128 + f * 16 + lrow;
        o[(size_t)row * 4096 + col] = f2bf(acc_o[f][i] / l_par[i]);
      }
  }
}

// ---------------------------------------------------------------
extern "C" void kernel_launch(void* const* d_in, const int* in_sizes, int n_in,
                              void* d_out, int out_size, void* d_ws, size_t ws_size,
                              hipStream_t stream) {
  (void)in_sizes; (void)n_in; (void)out_size; (void)ws_size;
  const float* hs   = (const float*)d_in[0];
  const float* Wqa  = (const float*)d_in[1];
  const float* qln  = (const float*)d_in[2];
  const float* Wqb  = (const float*)d_in[3];
  const float* Wkva = (const float*)d_in[4];
  const float* kvln = (const float*)d_in[5];
  const float* Wkvb = (const float*)d_in[6];
  const float* Wo   = (const float*)d_in[7];
  float* out = (float*)d_out;

  char* p = (char*)d_ws;
  size_t off = 0;
  auto carve = [&](size_t bytes) {
    char* r = p + off;
    off += (bytes + 255) & ~(size_t)255;
    return r;
  };
  u16* hs_bf = (u16*)carve((size_t)2048 * 4096 * 2);
  u16* WabT  = (u16*)carve((size_t)2112 * 4096 * 2);   // [0..1535]=WqaT, [1536..2111]=WkvaT
  u16* WqbT  = (u16*)carve((size_t)6144 * 1536 * 2);
  u16* WkvbT = (u16*)carve((size_t)8192 * 512 * 2);
  u16* WoT   = (u16*)carve((size_t)4096 * 4096 * 2);
  u16* fused = (u16*)carve((size_t)2048 * 2112 * 2);   // [qa | ckv] per row
  u16* qan   = (u16*)carve((size_t)2048 * 1536 * 2);
  u16* q     = (u16*)carve((size_t)2048 * 6144 * 2);
  u16* cn    = (u16*)carve((size_t)2048 * 512 * 2);
  u16* qfb   = (u16*)carve((size_t)32 * 2048 * 192 * 2);
  u16* kfb   = (u16*)carve((size_t)32 * 2048 * 192 * 2);
  u16* vTb   = (u16*)carve((size_t)32 * 128 * 2048 * 2);
  u16* ob    = (u16*)carve((size_t)2048 * 4096 * 2);
  float* cost = (float*)carve((size_t)65536 * 4);
  float* sint = (float*)carve((size_t)65536 * 4);

  // --- merged prep: cast + 5 transposes + rope table (1 launch) ---
  prep_merged_kernel<<<17984, 256, 0, stream>>>(hs, hs_bf, Wqa, Wkva, WabT,
                                                Wqb, WqbT, Wkvb, WkvbT, Wo, WoT,
                                                cost, sint);

  // --- fused first-stage GEMM: [qa | ckv] = hs @ [Wqa | Wkva] ---
  gemm_v3_kernel<1><<<dim3(17, 16), 256, 0, stream>>>(hs_bf, WabT, fused, nullptr, 2048, 2112, 4096);

  // --- merged norms (1 launch) ---
  norms_merged_kernel<<<4096, 256, 0, stream>>>(fused, qln, kvln, qan, cn);

  // --- merged q+kv second-stage GEMMs (1 launch; kv backfills q tail) ---
  gemm_qkv_kernel<<<dim3(64, 16, 2), 256, 0, stream>>>(qan, WqbT, q, cn, WkvbT, kfb, vTb);

  // --- merged builds: qf RoPE+scale, kf RoPE (1 launch) ---
  builds_merged_kernel<<<8192, 256, 0, stream>>>(q, fused + 1536, cost, sint, qfb, kfb);

  // --- attention v6 (512 blocks, 2/CU, KVBLK=32 dbuf + counted vmcnt) ---
  mla_attn_kernel<<<dim3(32, 16), 256, 0, stream>>>(qfb, kfb, vTb, ob);

  // --- output projection ---
  gemm_v3_kernel<0><<<dim3(32, 16), 256, 0, stream>>>(ob, WoT, out, nullptr, 2048, 4096, 4096);
}

// Round 15
// 399.096 us; speedup vs baseline: 1.1731x; 1.0100x over previous
//
#include <hip/hip_runtime.h>

typedef unsigned short u16;
using bf16x8 = __attribute__((ext_vector_type(8))) __bf16;
using f32x4  = __attribute__((ext_vector_type(4))) float;
using s16x8  = __attribute__((ext_vector_type(8))) short;
using s16x4  = __attribute__((ext_vector_type(4))) short;

#define AS1 __attribute__((address_space(1)))
#define AS3 __attribute__((address_space(3)))

__device__ __forceinline__ void gload16(const u16* g, u16* l) {
  __builtin_amdgcn_global_load_lds((AS1 void*)(size_t)g, (AS3 void*)l, 16, 0, 0);
}

__device__ __forceinline__ u16 f2bf(float f) {
  unsigned u = __float_as_uint(f);
  u += 0x7fffu + ((u >> 16) & 1u);   // round-to-nearest-even
  return (u16)(u >> 16);
}
__device__ __forceinline__ float bf2f(u16 h) {
  return __uint_as_float(((unsigned)h) << 16);
}

// ================= merged prep: cast + 5 transposes + rope table =================
__device__ __forceinline__ void transpose_tile(const float* __restrict__ W,
                                               u16* __restrict__ WT,
                                               int K, int N, int nb, int kb,
                                               u16 (*tile)[72]) {
  const int t = threadIdx.x;
  const int rr = t >> 3;        // 0..31
  const int cc = (t & 7) * 8;   // 0..56
#pragma unroll
  for (int pass = 0; pass < 2; ++pass) {
    const float* src = W + (size_t)(kb + pass * 32 + rr) * N + nb + cc;
    float4 a = *reinterpret_cast<const float4*>(src);
    float4 b = *reinterpret_cast<const float4*>(src + 4);
    u16* tr = &tile[pass * 32 + rr][cc];
    tr[0] = f2bf(a.x); tr[1] = f2bf(a.y); tr[2] = f2bf(a.z); tr[3] = f2bf(a.w);
    tr[4] = f2bf(b.x); tr[5] = f2bf(b.y); tr[6] = f2bf(b.z); tr[7] = f2bf(b.w);
  }
  __syncthreads();
#pragma unroll
  for (int pass = 0; pass < 2; ++pass) {
    s16x8 v;
#pragma unroll
    for (int j = 0; j < 8; ++j) v[j] = (short)tile[cc + j][pass * 32 + rr];
    *reinterpret_cast<s16x8*>(WT + (size_t)(nb + pass * 32 + rr) * K + kb + cc) = v;
  }
}

__global__ __launch_bounds__(256) void prep_merged_kernel(
    const float* __restrict__ hs, u16* __restrict__ hs_bf,
    const float* __restrict__ Wqa, const float* __restrict__ Wkva, u16* __restrict__ WabT,
    const float* __restrict__ Wqb, u16* __restrict__ WqbT,
    const float* __restrict__ Wkvb, u16* __restrict__ WkvbT,
    const float* __restrict__ Wo, u16* __restrict__ WoT,
    float* __restrict__ cost, float* __restrict__ sint) {
  __shared__ u16 tile[64][72];
  const int bid = blockIdx.x, t = threadIdx.x;
  if (bid < 8192) {                       // cast hs -> bf16
    int i = (bid * 256 + t) * 4;
    float4 v = *reinterpret_cast<const float4*>(hs + i);
    s16x4 o;
    o[0] = (short)f2bf(v.x); o[1] = (short)f2bf(v.y);
    o[2] = (short)f2bf(v.z); o[3] = (short)f2bf(v.w);
    *reinterpret_cast<s16x4*>(hs_bf + i) = o;
  } else if (bid < 9728) {                // Wqa [4096][1536] -> WabT[0..1536)
    int r = bid - 8192;
    transpose_tile(Wqa, WabT, 4096, 1536, (r % 24) * 64, (r / 24) * 64, tile);
  } else if (bid < 10304) {               // Wkva [4096][576] -> WabT[1536..2112)
    int r = bid - 9728;
    transpose_tile(Wkva, WabT + (size_t)1536 * 4096, 4096, 576, (r % 9) * 64, (r / 9) * 64, tile);
  } else if (bid < 12608) {               // Wqb [1536][6144]
    int r = bid - 10304;
    transpose_tile(Wqb, WqbT, 1536, 6144, (r % 96) * 64, (r / 96) * 64, tile);
  } else if (bid < 13632) {               // Wkvb [512][8192]
    int r = bid - 12608;
    transpose_tile(Wkvb, WkvbT, 512, 8192, (r % 128) * 64, (r / 128) * 64, tile);
  } else if (bid < 17728) {               // Wo [4096][4096]
    int r = bid - 13632;
    transpose_tile(Wo, WoT, 4096, 4096, (r % 64) * 64, (r / 64) * 64, tile);
  } else {                                // rope table
    int idx = (bid - 17728) * 256 + t;    // 65536
    int pos = idx >> 5, j = idx & 31;
    float inv = __expf(-(float)j * (9.210340371976184f / 32.0f));
    float f = (float)pos * inv;
    cost[idx] = cosf(f);
    sint[idx] = sinf(f);
  }
}

// ================= merged rmsnorms =================
__global__ __launch_bounds__(256) void norms_merged_kernel(const u16* __restrict__ fused,
                                                           const float* __restrict__ qln,
                                                           const float* __restrict__ kvln,
                                                           u16* __restrict__ qan,
                                                           u16* __restrict__ cn) {
  const int bid = blockIdx.x, t = threadIdx.x;
  const int row = bid & 2047;
  const bool is_q = bid < 2048;
  const int R = is_q ? 1536 : 512;
  const u16* xr = fused + (size_t)row * 2112 + (is_q ? 0 : 1536);
  const float* w = is_q ? qln : kvln;
  u16* yr = (is_q ? qan + (size_t)row * 1536 : cn + (size_t)row * 512);
  float ss = 0.f;
  for (int i = t; i < R; i += 256) { float f = bf2f(xr[i]); ss += f * f; }
#pragma unroll
  for (int m = 32; m >= 1; m >>= 1) ss += __shfl_xor(ss, m);
  __shared__ float red[4];
  if ((t & 63) == 0) red[t >> 6] = ss;
  __syncthreads();
  float tot = red[0] + red[1] + red[2] + red[3];
  float r = rsqrtf(tot / (float)R + 1e-6f);
  for (int i = t; i < R; i += 256) yr[i] = f2bf(bf2f(xr[i]) * r * w[i]);
}

// ================= merged builds: qf (RoPE+scale) + kf rope-only =================
__global__ __launch_bounds__(256) void builds_merged_kernel(const u16* __restrict__ q,
                                                            const u16* __restrict__ ckv,
                                                            const float* __restrict__ cost,
                                                            const float* __restrict__ sint,
                                                            u16* __restrict__ qf,
                                                            u16* __restrict__ kf) {
  const int bid = blockIdx.x, t = threadIdx.x;
  if (bid < 6144) {
    int o8 = (bid * 256 + t) * 8;
    const float scale = 0.07216878364870323f;  // 192^-0.5 folded into q
    int c = (o8 % 192) >> 3;
    int rest = o8 / 192;
    int s = rest & 2047, h = rest >> 11;
    const u16* qrow = q + ((size_t)s * 32 + h) * 192;
    s16x8 out;
    if (c < 16) {
      s16x8 v = *reinterpret_cast<const s16x8*>(qrow + c * 8);
#pragma unroll
      for (int j = 0; j < 8; ++j) out[j] = (short)f2bf(bf2f((u16)v[j]) * scale);
    } else {
      int j0 = c * 8 - 128;
      bool lo = j0 < 32;
      int jj0 = lo ? j0 : j0 - 32;
      s16x8 a = *reinterpret_cast<const s16x8*>(qrow + 128 + 2 * jj0);
      s16x8 b = *reinterpret_cast<const s16x8*>(qrow + 128 + 2 * jj0 + 8);
      float4 c0 = *reinterpret_cast<const float4*>(cost + s * 32 + jj0);
      float4 c1 = *reinterpret_cast<const float4*>(cost + s * 32 + jj0 + 4);
      float4 s0 = *reinterpret_cast<const float4*>(sint + s * 32 + jj0);
      float4 s1 = *reinterpret_cast<const float4*>(sint + s * 32 + jj0 + 4);
      float cs[8] = {c0.x, c0.y, c0.z, c0.w, c1.x, c1.y, c1.z, c1.w};
      float sn[8] = {s0.x, s0.y, s0.z, s0.w, s1.x, s1.y, s1.z, s1.w};
#pragma unroll
      for (int j = 0; j < 8; ++j) {
        float x0 = bf2f((u16)((j < 4) ? a[2 * j] : b[2 * j - 8]));
        float x1 = bf2f((u16)((j < 4) ? a[2 * j + 1] : b[2 * j - 7]));
        float v = lo ? (x0 * cs[j] - x1 * sn[j]) : (x1 * cs[j] + x0 * sn[j]);
        out[j] = (short)f2bf(v * scale);
      }
    }
    *reinterpret_cast<s16x8*>(qf + o8) = out;
  } else {
    int o8 = ((bid - 6144) * 256 + t) * 8;   // 32*2048*64 range
    int j0 = o8 & 63;
    int rest = o8 >> 6;
    int s = rest & 2047, h = rest >> 11;
    bool lo = j0 < 32;
    int jj0 = lo ? j0 : j0 - 32;
    const u16* crow = ckv + (size_t)s * 2112 + 512;
    s16x8 a = *reinterpret_cast<const s16x8*>(crow + 2 * jj0);
    s16x8 b = *reinterpret_cast<const s16x8*>(crow + 2 * jj0 + 8);
    float4 c0 = *reinterpret_cast<const float4*>(cost + s * 32 + jj0);
    float4 c1 = *reinterpret_cast<const float4*>(cost + s * 32 + jj0 + 4);
    float4 s0 = *reinterpret_cast<const float4*>(sint + s * 32 + jj0);
    float4 s1 = *reinterpret_cast<const float4*>(sint + s * 32 + jj0 + 4);
    float cs[8] = {c0.x, c0.y, c0.z, c0.w, c1.x, c1.y, c1.z, c1.w};
    float sn[8] = {s0.x, s0.y, s0.z, s0.w, s1.x, s1.y, s1.z, s1.w};
    s16x8 out;
#pragma unroll
    for (int j = 0; j < 8; ++j) {
      float x0 = bf2f((u16)((j < 4) ? a[2 * j] : b[2 * j - 8]));
      float x1 = bf2f((u16)((j < 4) ? a[2 * j + 1] : b[2 * j - 7]));
      float v = lo ? (x0 * cs[j] - x1 * sn[j]) : (x1 * cs[j] + x0 * sn[j]);
      out[j] = (short)f2bf(v);
    }
    *reinterpret_cast<s16x8*>(kf + ((size_t)h * 2048 + s) * 192 + 128 + j0) = out;
  }
}

// ---------------- GEMM v3 body (128x128, for ragged fused1) ----------------
template <int EPI>
__device__ __forceinline__ void gemm_v3_body(const u16* __restrict__ A,
                                             const u16* __restrict__ BT,
                                             void* __restrict__ Cv,
                                             void* __restrict__ Cv2,
                                             int M, int N, int K,
                                             int bx, int by, u16* S) {
  const int t0 = threadIdx.x;
  const int lane = t0 & 63, wave = t0 >> 6;
  const int wr = wave >> 1, wc = wave & 1;
  const int row0 = by * 128, col0 = bx * 128;
  const int lrow = lane & 15, lkg = lane >> 4;

  const int lp = lane ^ ((lane >> 3) & 3);
  const int srow_off = lp >> 2;
  const int skel = (lp & 3) * 8;
  const int c0 = wave * 2, c1 = c0 + 1;
  const int arow_c0 = row0 + c0 * 16 + srow_off;
  const int arow_c1 = row0 + c1 * 16 + srow_off;
  int brow_c0 = col0 + c0 * 16 + srow_off; if (brow_c0 > N - 1) brow_c0 = N - 1;
  int brow_c1 = col0 + c1 * 16 + srow_off; if (brow_c1 > N - 1) brow_c1 = N - 1;

  int aoff[4], boff[4];
#pragma unroll
  for (int m = 0; m < 4; ++m) {
    int r = wr * 64 + m * 16 + lrow;
    int off = r * 32 + lkg * 8;
    aoff[m] = off ^ ((off >> 3) & 0x18);
    r = wc * 64 + m * 16 + lrow;
    off = r * 32 + lkg * 8;
    boff[m] = off ^ ((off >> 3) & 0x18);
  }

  const int NT = K >> 5;

#pragma unroll
  for (int pt = 0; pt < 3; ++pt) {
    u16* ab = &S[pt * 8192];
    const int kb = pt * 32 + skel;
    gload16(A  + (size_t)arow_c0 * K + kb, ab + c0 * 512);
    gload16(A  + (size_t)arow_c1 * K + kb, ab + c1 * 512);
    gload16(BT + (size_t)brow_c0 * K + kb, ab + 4096 + c0 * 512);
    gload16(BT + (size_t)brow_c1 * K + kb, ab + 4096 + c1 * 512);
  }

  f32x4 acc[4][4];
#pragma unroll
  for (int m = 0; m < 4; ++m)
#pragma unroll
    for (int n = 0; n < 4; ++n) acc[m][n] = 0.f;

  for (int t = 0; t < NT; ++t) {
    if (t + 2 < NT)      asm volatile("s_waitcnt vmcnt(8)" ::: "memory");
    else if (t + 1 < NT) asm volatile("s_waitcnt vmcnt(4)" ::: "memory");
    else                 asm volatile("s_waitcnt vmcnt(0)" ::: "memory");
    __builtin_amdgcn_s_barrier();
    __builtin_amdgcn_sched_barrier(0);

    const u16* ab = &S[(t & 3) * 8192];
    bf16x8 af[4], bb[4];
#pragma unroll
    for (int m = 0; m < 4; ++m)
      af[m] = *reinterpret_cast<const bf16x8*>(ab + aoff[m]);
#pragma unroll
    for (int n = 0; n < 4; ++n)
      bb[n] = *reinterpret_cast<const bf16x8*>(ab + 4096 + boff[n]);

    if (t + 3 < NT) {
      u16* sb = &S[((t + 3) & 3) * 8192];
      const int kb = (t + 3) * 32 + skel;
      gload16(A  + (size_t)arow_c0 * K + kb, sb + c0 * 512);
      gload16(A  + (size_t)arow_c1 * K + kb, sb + c1 * 512);
      gload16(BT + (size_t)brow_c0 * K + kb, sb + 4096 + c0 * 512);
      gload16(BT + (size_t)brow_c1 * K + kb, sb + 4096 + c1 * 512);
    }

    __builtin_amdgcn_s_setprio(1);
#pragma unroll
    for (int m = 0; m < 4; ++m)
#pragma unroll
      for (int n = 0; n < 4; ++n)
        acc[m][n] = __builtin_amdgcn_mfma_f32_16x16x32_bf16(af[m], bb[n], acc[m][n], 0, 0, 0);
    __builtin_amdgcn_s_setprio(0);
  }

#pragma unroll
  for (int m = 0; m < 4; ++m) {
#pragma unroll
    for (int n = 0; n < 4; ++n) {
      int col = col0 + wc * 64 + n * 16 + lrow;
      int row = row0 + wr * 64 + m * 16 + lkg * 4;
      if (col < N) {
#pragma unroll
        for (int i = 0; i < 4; ++i) {
          size_t idx = (size_t)(row + i) * N + col;
          if (EPI == 1) ((u16*)Cv)[idx] = f2bf(acc[m][n][i]);
          else          ((float*)Cv)[idx] = acc[m][n][i];
        }
      }
    }
  }
}

template <int EPI>
__global__ __launch_bounds__(256) void gemm_v3_kernel(const u16* __restrict__ A,
                                                      const u16* __restrict__ BT,
                                                      void* __restrict__ Cv,
                                                      void* __restrict__ Cv2,
                                                      int M, int N, int K) {
  __shared__ __align__(16) u16 S[4 * 8192];
  gemm_v3_body<EPI>(A, BT, Cv, Cv2, M, N, K, blockIdx.x, blockIdx.y, S);
}

// ---------------- GEMM v4 body: 128(M)x256(N) tile, per-wave 64x128 ----------------
// 4 waves (2x2). LDS-read ratio 0.375 KB/MFMA (vs 0.5 in v3), 128 MFMA/block/K-step.
// 3-deep LDS pipeline (72KB -> 2 blocks/CU at <=224 VGPR... compiler-bounded (256,2)),
// 6 staging loads/lane/tile, steady-state vmcnt(12). Swizzle identical to v3
// (16-row x 32-col chunks). A-frags (4) register-held; B-frags streamed per n.
// EPI: 0 = f32 C, 1 = bf16 C, 2 = MLA-kv split (kf nope + vT direct).
template <int EPI>
__device__ __forceinline__ void gemm_v4_body(const u16* __restrict__ A,
                                             const u16* __restrict__ BT,
                                             void* __restrict__ Cv,
                                             void* __restrict__ Cv2,
                                             int M, int N, int K,
                                             int bx, int by, u16* S) {
  const int t0 = threadIdx.x;
  const int lane = t0 & 63, wave = t0 >> 6;
  const int wr = wave >> 1, wc = wave & 1;
  const int row0 = by * 128, col0 = bx * 256;
  const int lrow = lane & 15, lkg = lane >> 4;

  const int lp = lane ^ ((lane >> 3) & 3);
  const int srow_off = lp >> 2;
  const int skel = (lp & 3) * 8;

  // staging: wave stages A chunks {2w,2w+1}, B chunks {4w..4w+3} (chunks = 16 rows)
  const int ac0 = wave * 2, ac1 = ac0 + 1;
  const int arow_0 = row0 + ac0 * 16 + srow_off;
  const int arow_1 = row0 + ac1 * 16 + srow_off;
  int brow[4];
#pragma unroll
  for (int j = 0; j < 4; ++j) {
    int r = col0 + (wave * 4 + j) * 16 + srow_off;
    brow[j] = (r > N - 1) ? (N - 1) : r;
  }

  int aoff[4], boff[8];
#pragma unroll
  for (int m = 0; m < 4; ++m) {
    int r = wr * 64 + m * 16 + lrow;
    int off = r * 32 + lkg * 8;
    aoff[m] = off ^ ((off >> 3) & 0x18);
  }
#pragma unroll
  for (int n = 0; n < 8; ++n) {
    int r = wc * 128 + n * 16 + lrow;
    int off = r * 32 + lkg * 8;
    boff[n] = off ^ ((off >> 3) & 0x18);
  }

  const int NT = K >> 5;

  // prologue: stage tiles 0,1
#pragma unroll
  for (int pt = 0; pt < 2; ++pt) {
    u16* sb = &S[pt * 12288];
    const int kb = pt * 32 + skel;
    gload16(A + (size_t)arow_0 * K + kb, sb + ac0 * 512);
    gload16(A + (size_t)arow_1 * K + kb, sb + ac1 * 512);
#pragma unroll
    for (int j = 0; j < 4; ++j)
      gload16(BT + (size_t)brow[j] * K + kb, sb + 4096 + (wave * 4 + j) * 512);
  }

  f32x4 acc[4][8];
#pragma unroll
  for (int m = 0; m < 4; ++m)
#pragma unroll
    for (int n = 0; n < 8; ++n) acc[m][n] = 0.f;

  int bufr = 0, bufw = 2;
  for (int t = 0; t < NT; ++t) {
    if (t + 2 < NT) {
      u16* sb = &S[bufw * 12288];
      const int kb = (t + 2) * 32 + skel;
      gload16(A + (size_t)arow_0 * K + kb, sb + ac0 * 512);
      gload16(A + (size_t)arow_1 * K + kb, sb + ac1 * 512);
#pragma unroll
      for (int j = 0; j < 4; ++j)
        gload16(BT + (size_t)brow[j] * K + kb, sb + 4096 + (wave * 4 + j) * 512);
      bufw = (bufw + 1 == 3) ? 0 : bufw + 1;
      asm volatile("s_waitcnt vmcnt(12)" ::: "memory");   // tile t landed; t+1,t+2 in flight
    } else if (t + 1 < NT) {
      asm volatile("s_waitcnt vmcnt(6)" ::: "memory");
    } else {
      asm volatile("s_waitcnt vmcnt(0)" ::: "memory");
    }
    __builtin_amdgcn_s_barrier();
    __builtin_amdgcn_sched_barrier(0);

    const u16* ab = &S[bufr * 12288];
    bufr = (bufr + 1 == 3) ? 0 : bufr + 1;
    bf16x8 af[4];
#pragma unroll
    for (int m = 0; m < 4; ++m)
      af[m] = *reinterpret_cast<const bf16x8*>(ab + aoff[m]);

    __builtin_amdgcn_s_setprio(1);
#pragma unroll
    for (int n = 0; n < 8; ++n) {
      bf16x8 bbn = *reinterpret_cast<const bf16x8*>(ab + 4096 + boff[n]);
#pragma unroll
      for (int m = 0; m < 4; ++m)
        acc[m][n] = __builtin_amdgcn_mfma_f32_16x16x32_bf16(af[m], bbn, acc[m][n], 0, 0, 0);
    }
    __builtin_amdgcn_s_setprio(0);
  }

#pragma unroll
  for (int m = 0; m < 4; ++m) {
#pragma unroll
    for (int n = 0; n < 8; ++n) {
      int col = col0 + wc * 128 + n * 16 + lrow;
      int row = row0 + wr * 64 + m * 16 + lkg * 4;
      if (EPI == 2) {
        int d = col & 255, hh = col >> 8;
        if (d < 128) {
          u16* dst = (u16*)Cv + ((size_t)hh * 2048 + row) * 192 + d;
#pragma unroll
          for (int i = 0; i < 4; ++i) dst[(size_t)i * 192] = f2bf(acc[m][n][i]);
        } else {
          s16x4 v;
#pragma unroll
          for (int i = 0; i < 4; ++i) v[i] = (short)f2bf(acc[m][n][i]);
          *reinterpret_cast<s16x4*>((u16*)Cv2 + ((size_t)hh * 128 + (d - 128)) * 2048 + row) = v;
        }
      } else if (col < N) {
#pragma unroll
        for (int i = 0; i < 4; ++i) {
          size_t idx = (size_t)(row + i) * N + col;
          if (EPI == 1) ((u16*)Cv)[idx] = f2bf(acc[m][n][i]);
          else          ((float*)Cv)[idx] = acc[m][n][i];
        }
      }
    }
  }
}

template <int EPI>
__global__ __launch_bounds__(256, 2) void gemm_v4_kernel(const u16* __restrict__ A,
                                                         const u16* __restrict__ BT,
                                                         void* __restrict__ Cv,
                                                         void* __restrict__ Cv2,
                                                         int M, int N, int K) {
  __shared__ __align__(16) u16 S[3 * 12288];
  gemm_v4_body<EPI>(A, BT, Cv, Cv2, M, N, K, blockIdx.x, blockIdx.y, S);
}

// merged q-GEMM (z=0) + kv-GEMM (z=1), v4 tiles (N multiples of 256 -> exact)
__global__ __launch_bounds__(256, 2) void gemm_qkv_kernel(const u16* __restrict__ qan,
                                                          const u16* __restrict__ WqbT,
                                                          u16* __restrict__ qout,
                                                          const u16* __restrict__ cn,
                                                          const u16* __restrict__ WkvbT,
                                                          u16* __restrict__ kfb,
                                                          u16* __restrict__ vTb) {
  __shared__ __align__(16) u16 S[3 * 12288];
  if (blockIdx.z == 0) {
    if (blockIdx.x >= 24) return;
    gemm_v4_body<1>(qan, WqbT, qout, nullptr, 2048, 6144, 1536, blockIdx.x, blockIdx.y, S);
  } else {
    gemm_v4_body<2>(cn, WkvbT, kfb, vTb, 2048, 8192, 512, blockIdx.x, blockIdx.y, S);
  }
}

// ---------------- causal flash attention v6 (kept from r14: 129us, 0 bank conflicts) ----------------
__global__ __launch_bounds__(256) void mla_attn_kernel(const u16* __restrict__ qf,
                                                       const u16* __restrict__ kf,
                                                       const u16* __restrict__ vT,
                                                       u16* __restrict__ o) {
  const int h = blockIdx.x, pair = blockIdx.y;
  const int t = threadIdx.x, wave = t >> 6, lane = t & 63;
  const int lrow = lane & 15, lkg = lane >> 4;
  __shared__ __align__(16) u16 Kt[2][12 * 512];
  __shared__ __align__(16) u16 Vt[2][8 * 512];
  __shared__ __align__(16) u16 Pl[4][16][36];

  const u16* ksrc[3]; u16 *kdst0[3], *kdst1[3];
#pragma unroll
  for (int i = 0; i < 3; ++i) {
    int c = wave * 3 + i, cg = c / 6, kk = c - cg * 6;
    ksrc[i] = kf + ((size_t)h * 2048 + cg * 16 + lrow) * 192 + kk * 32 + lkg * 8;
    kdst0[i] = &Kt[0][c * 512];
    kdst1[i] = &Kt[1][c * 512];
  }
  const u16* vsrc[2]; u16 *vdst0[2], *vdst1[2];
#pragma unroll
  for (int j = 0; j < 2; ++j) {
    int f = wave * 2 + j;
    vsrc[j] = vT + ((size_t)h * 128 + f * 16 + lrow) * 2048 + lkg * 8;
    vdst0[j] = &Vt[0][f * 512];
    vdst1[j] = &Vt[1][f * 512];
  }

  for (int qq = 0; qq < 2; ++qq) {
    const int qb = qq ? (31 - pair) : pair;
    const int qbase = qb * 64 + wave * 16;

    bf16x8 qfr[6];
    const u16* qrow_ptr = qf + ((size_t)h * 2048 + qbase + lrow) * 192;
#pragma unroll
    for (int kk = 0; kk < 6; ++kk)
      qfr[kk] = *reinterpret_cast<const bf16x8*>(qrow_ptr + kk * 32 + lkg * 8);

    f32x4 acc_o[8];
#pragma unroll
    for (int f = 0; f < 8; ++f) acc_o[f] = 0.f;
    float m_run[4], l_par[4];
#pragma unroll
    for (int i = 0; i < 4; ++i) { m_run[i] = -1e30f; l_par[i] = 0.f; }

    const int nt = 2 * qb + 2;

#pragma unroll
    for (int i = 0; i < 3; ++i) gload16(ksrc[i], kdst0[i]);
#pragma unroll
    for (int j = 0; j < 2; ++j) gload16(vsrc[j], vdst0[j]);

    for (int it = 0; it < nt; ++it) {
      const int kt = it * 32;
      if (it + 1 < nt) {
        const int nb = (it + 1) & 1;
        const size_t kadv = (size_t)(it + 1) * 32 * 192;
        const size_t vadv = (size_t)(it + 1) * 32;
#pragma unroll
        for (int i = 0; i < 3; ++i) gload16(ksrc[i] + kadv, nb ? kdst1[i] : kdst0[i]);
#pragma unroll
        for (int j = 0; j < 2; ++j) gload16(vsrc[j] + vadv, nb ? vdst1[j] : vdst0[j]);
        asm volatile("s_waitcnt vmcnt(5)" ::: "memory");
      } else {
        asm volatile("s_waitcnt vmcnt(0)" ::: "memory");
      }
      __builtin_amdgcn_s_barrier();
      __builtin_amdgcn_sched_barrier(0);

      const u16* Kb = &Kt[it & 1][0];
      const u16* Vb = &Vt[it & 1][0];
      if (kt <= qbase + 15) {
        f32x4 sv[2];
        sv[0] = 0.f; sv[1] = 0.f;
#pragma unroll
        for (int cg = 0; cg < 2; ++cg)
#pragma unroll
          for (int kk = 0; kk < 6; ++kk) {
            bf16x8 kfr = *reinterpret_cast<const bf16x8*>(&Kb[(cg * 6 + kk) * 512 + lane * 8]);
            sv[cg] = __builtin_amdgcn_mfma_f32_16x16x32_bf16(qfr[kk], kfr, sv[cg], 0, 0, 0);
          }
        const int qrow_b = qbase + lkg * 4;
        if (kt + 31 > qbase) {
#pragma unroll
          for (int cg = 0; cg < 2; ++cg) {
            int kvcol = kt + cg * 16 + lrow;
#pragma unroll
            for (int i = 0; i < 4; ++i)
              if (kvcol > qrow_b + i) sv[cg][i] = -__builtin_inff();
          }
        }
        float tmax[4];
#pragma unroll
        for (int i = 0; i < 4; ++i) tmax[i] = fmaxf(sv[0][i], sv[1][i]);
#pragma unroll
        for (int m = 8; m >= 1; m >>= 1)
#pragma unroll
          for (int i = 0; i < 4; ++i) tmax[i] = fmaxf(tmax[i], __shfl_xor(tmax[i], m));
        int need = 0;
#pragma unroll
        for (int i = 0; i < 4; ++i) need |= (tmax[i] > m_run[i] + 8.f) ? 1 : 0;
        if (__any(need)) {
#pragma unroll
          for (int i = 0; i < 4; ++i) {
            float mnew = fmaxf(m_run[i], tmax[i]);
            float alpha = __expf(m_run[i] - mnew);
            m_run[i] = mnew;
            l_par[i] *= alpha;
#pragma unroll
            for (int f = 0; f < 8; ++f) acc_o[f][i] *= alpha;
          }
        }
#pragma unroll
        for (int i = 0; i < 4; ++i) {
          sv[0][i] = __expf(sv[0][i] - m_run[i]);
          sv[1][i] = __expf(sv[1][i] - m_run[i]);
          l_par[i] += sv[0][i] + sv[1][i];
        }
#pragma unroll
        for (int cg = 0; cg < 2; ++cg)
#pragma unroll
          for (int i = 0; i < 4; ++i)
            Pl[wave][lkg * 4 + i][cg * 16 + lrow] = f2bf(sv[cg][i]);
        bf16x8 pf = *reinterpret_cast<const bf16x8*>(&Pl[wave][lrow][lkg * 8]);
#pragma unroll
        for (int f = 0; f < 8; ++f) {
          bf16x8 vfr = *reinterpret_cast<const bf16x8*>(&Vb[f * 512 + lane * 8]);
          acc_o[f] = __builtin_amdgcn_mfma_f32_16x16x32_bf16(pf, vfr, acc_o[f], 0, 0, 0);
        }
      }
      __builtin_amdgcn_sched_barrier(0);
      __builtin_amdgcn_s_barrier();
    }
#pragma unroll
    for (int i = 0; i < 4; ++i)
#pragma unroll
      for (int m = 8; m >= 1; m >>= 1) l_par[i] += __shfl_xor(l_par[i], m);
#pragma unroll
    for (int f = 0; f < 8; ++f)
#pragma unroll
      for (int i = 0; i < 4; ++i) {
        int row = qbase + lkg * 4 + i;
        int col = h * 128 + f * 16 + lrow;
        o[(size_t)row * 4096 + col] = f2bf(acc_o[f][i] / l_par[i]);
      }
  }
}

// ---------------------------------------------------------------
extern "C" void kernel_launch(void* const* d_in, const int* in_sizes, int n_in,
                              void* d_out, int out_size, void* d_ws, size_t ws_size,
                              hipStream_t stream) {
  (void)in_sizes; (void)n_in; (void)out_size; (void)ws_size;
  const float* hs   = (const float*)d_in[0];
  const float* Wqa  = (const float*)d_in[1];
  const float* qln  = (const float*)d_in[2];
  const float* Wqb  = (const float*)d_in[3];
  const float* Wkva = (const float*)d_in[4];
  const float* kvln = (const float*)d_in[5];
  const float* Wkvb = (const float*)d_in[6];
  const float* Wo   = (const float*)d_in[7];
  float* out = (float*)d_out;

  char* p = (char*)d_ws;
  size_t off = 0;
  auto carve = [&](size_t bytes) {
    char* r = p + off;
    off += (bytes + 255) & ~(size_t)255;
    return r;
  };
  u16* hs_bf = (u16*)carve((size_t)2048 * 4096 * 2);
  u16* WabT  = (u16*)carve((size_t)2112 * 4096 * 2);   // [0..1535]=WqaT, [1536..2111]=WkvaT
  u16* WqbT  = (u16*)carve((size_t)6144 * 1536 * 2);
  u16* WkvbT = (u16*)carve((size_t)8192 * 512 * 2);
  u16* WoT   = (u16*)carve((size_t)4096 * 4096 * 2);
  u16* fused = (u16*)carve((size_t)2048 * 2112 * 2);   // [qa | ckv] per row
  u16* qan   = (u16*)carve((size_t)2048 * 1536 * 2);
  u16* q     = (u16*)carve((size_t)2048 * 6144 * 2);
  u16* cn    = (u16*)carve((size_t)2048 * 512 * 2);
  u16* qfb   = (u16*)carve((size_t)32 * 2048 * 192 * 2);
  u16* kfb   = (u16*)carve((size_t)32 * 2048 * 192 * 2);
  u16* vTb   = (u16*)carve((size_t)32 * 128 * 2048 * 2);
  u16* ob    = (u16*)carve((size_t)2048 * 4096 * 2);
  float* cost = (float*)carve((size_t)65536 * 4);
  float* sint = (float*)carve((size_t)65536 * 4);

  // --- merged prep: cast + 5 transposes + rope table (1 launch) ---
  prep_merged_kernel<<<17984, 256, 0, stream>>>(hs, hs_bf, Wqa, Wkva, WabT,
                                                Wqb, WqbT, Wkvb, WkvbT, Wo, WoT,
                                                cost, sint);

  // --- fused first-stage GEMM (ragged N=2112 -> v3) ---
  gemm_v3_kernel<1><<<dim3(17, 16), 256, 0, stream>>>(hs_bf, WabT, fused, nullptr, 2048, 2112, 4096);

  // --- merged norms (1 launch) ---
  norms_merged_kernel<<<4096, 256, 0, stream>>>(fused, qln, kvln, qan, cn);

  // --- merged q+kv second-stage GEMMs (v4 tiles; exact-fit N) ---
  gemm_qkv_kernel<<<dim3(32, 16, 2), 256, 0, stream>>>(qan, WqbT, q, cn, WkvbT, kfb, vTb);

  // --- merged builds: qf RoPE+scale, kf RoPE (1 launch) ---
  builds_merged_kernel<<<8192, 256, 0, stream>>>(q, fused + 1536, cost, sint, qfb, kfb);

  // --- attention v6 (512 blocks, 2/CU, KVBLK=32 dbuf + counted vmcnt) ---
  mla_attn_kernel<<<dim3(32, 16), 256, 0, stream>>>(qfb, kfb, vTb, ob);

  // --- output projection (v4: 16x16 = 256 blocks, exact 1/CU) ---
  gemm_v4_kernel<0><<<dim3(16, 16), 256, 0, stream>>>(ob, WoT, out, nullptr, 2048, 4096, 4096);
}

// Round 16
// 393.777 us; speedup vs baseline: 1.1890x; 1.0135x over previous
//
#include <hip/hip_runtime.h>

typedef unsigned short u16;
using bf16x8 = __attribute__((ext_vector_type(8))) __bf16;
using f32x4  = __attribute__((ext_vector_type(4))) float;
using s16x8  = __attribute__((ext_vector_type(8))) short;
using s16x4  = __attribute__((ext_vector_type(4))) short;

#define AS1 __attribute__((address_space(1)))
#define AS3 __attribute__((address_space(3)))

__device__ __forceinline__ void gload16(const u16* g, u16* l) {
  __builtin_amdgcn_global_load_lds((AS1 void*)(size_t)g, (AS3 void*)l, 16, 0, 0);
}

__device__ __forceinline__ u16 f2bf(float f) {
  unsigned u = __float_as_uint(f);
  u += 0x7fffu + ((u >> 16) & 1u);   // round-to-nearest-even
  return (u16)(u >> 16);
}
__device__ __forceinline__ float bf2f(u16 h) {
  return __uint_as_float(((unsigned)h) << 16);
}

// ================= merged prep: cast + 5 transposes + rope table =================
__device__ __forceinline__ void transpose_tile(const float* __restrict__ W,
                                               u16* __restrict__ WT,
                                               int K, int N, int nb, int kb,
                                               u16 (*tile)[72]) {
  const int t = threadIdx.x;
  const int rr = t >> 3;        // 0..31
  const int cc = (t & 7) * 8;   // 0..56
#pragma unroll
  for (int pass = 0; pass < 2; ++pass) {
    const float* src = W + (size_t)(kb + pass * 32 + rr) * N + nb + cc;
    float4 a = *reinterpret_cast<const float4*>(src);
    float4 b = *reinterpret_cast<const float4*>(src + 4);
    u16* tr = &tile[pass * 32 + rr][cc];
    tr[0] = f2bf(a.x); tr[1] = f2bf(a.y); tr[2] = f2bf(a.z); tr[3] = f2bf(a.w);
    tr[4] = f2bf(b.x); tr[5] = f2bf(b.y); tr[6] = f2bf(b.z); tr[7] = f2bf(b.w);
  }
  __syncthreads();
#pragma unroll
  for (int pass = 0; pass < 2; ++pass) {
    s16x8 v;
#pragma unroll
    for (int j = 0; j < 8; ++j) v[j] = (short)tile[cc + j][pass * 32 + rr];
    *reinterpret_cast<s16x8*>(WT + (size_t)(nb + pass * 32 + rr) * K + kb + cc) = v;
  }
}

__global__ __launch_bounds__(256) void prep_merged_kernel(
    const float* __restrict__ hs, u16* __restrict__ hs_bf,
    const float* __restrict__ Wqa, const float* __restrict__ Wkva, u16* __restrict__ WabT,
    const float* __restrict__ Wqb, u16* __restrict__ WqbT,
    const float* __restrict__ Wkvb, u16* __restrict__ WkvbT,
    const float* __restrict__ Wo, u16* __restrict__ WoT,
    float* __restrict__ cost, float* __restrict__ sint) {
  __shared__ u16 tile[64][72];
  const int bid = blockIdx.x, t = threadIdx.x;
  if (bid < 8192) {                       // cast hs -> bf16
    int i = (bid * 256 + t) * 4;
    float4 v = *reinterpret_cast<const float4*>(hs + i);
    s16x4 o;
    o[0] = (short)f2bf(v.x); o[1] = (short)f2bf(v.y);
    o[2] = (short)f2bf(v.z); o[3] = (short)f2bf(v.w);
    *reinterpret_cast<s16x4*>(hs_bf + i) = o;
  } else if (bid < 9728) {                // Wqa [4096][1536] -> WabT[0..1536)
    int r = bid - 8192;
    transpose_tile(Wqa, WabT, 4096, 1536, (r % 24) * 64, (r / 24) * 64, tile);
  } else if (bid < 10304) {               // Wkva [4096][576] -> WabT[1536..2112)
    int r = bid - 9728;
    transpose_tile(Wkva, WabT + (size_t)1536 * 4096, 4096, 576, (r % 9) * 64, (r / 9) * 64, tile);
  } else if (bid < 12608) {               // Wqb [1536][6144]
    int r = bid - 10304;
    transpose_tile(Wqb, WqbT, 1536, 6144, (r % 96) * 64, (r / 96) * 64, tile);
  } else if (bid < 13632) {               // Wkvb [512][8192]
    int r = bid - 12608;
    transpose_tile(Wkvb, WkvbT, 512, 8192, (r % 128) * 64, (r / 128) * 64, tile);
  } else if (bid < 17728) {               // Wo [4096][4096]
    int r = bid - 13632;
    transpose_tile(Wo, WoT, 4096, 4096, (r % 64) * 64, (r / 64) * 64, tile);
  } else {                                // rope table
    int idx = (bid - 17728) * 256 + t;    // 65536
    int pos = idx >> 5, j = idx & 31;
    float inv = __expf(-(float)j * (9.210340371976184f / 32.0f));
    float f = (float)pos * inv;
    cost[idx] = cosf(f);
    sint[idx] = sinf(f);
  }
}

// ================= merged rmsnorms =================
__global__ __launch_bounds__(256) void norms_merged_kernel(const u16* __restrict__ fused,
                                                           const float* __restrict__ qln,
                                                           const float* __restrict__ kvln,
                                                           u16* __restrict__ qan,
                                                           u16* __restrict__ cn) {
  const int bid = blockIdx.x, t = threadIdx.x;
  const int row = bid & 2047;
  const bool is_q = bid < 2048;
  const int R = is_q ? 1536 : 512;
  const u16* xr = fused + (size_t)row * 2112 + (is_q ? 0 : 1536);
  const float* w = is_q ? qln : kvln;
  u16* yr = (is_q ? qan + (size_t)row * 1536 : cn + (size_t)row * 512);
  float ss = 0.f;
  for (int i = t; i < R; i += 256) { float f = bf2f(xr[i]); ss += f * f; }
#pragma unroll
  for (int m = 32; m >= 1; m >>= 1) ss += __shfl_xor(ss, m);
  __shared__ float red[4];
  if ((t & 63) == 0) red[t >> 6] = ss;
  __syncthreads();
  float tot = red[0] + red[1] + red[2] + red[3];
  float r = rsqrtf(tot / (float)R + 1e-6f);
  for (int i = t; i < R; i += 256) yr[i] = f2bf(bf2f(xr[i]) * r * w[i]);
}

// ================= merged builds: qf (RoPE+scale) + kf rope-only =================
__global__ __launch_bounds__(256) void builds_merged_kernel(const u16* __restrict__ q,
                                                            const u16* __restrict__ ckv,
                                                            const float* __restrict__ cost,
                                                            const float* __restrict__ sint,
                                                            u16* __restrict__ qf,
                                                            u16* __restrict__ kf) {
  const int bid = blockIdx.x, t = threadIdx.x;
  if (bid < 6144) {
    int o8 = (bid * 256 + t) * 8;
    const float scale = 0.07216878364870323f;  // 192^-0.5 folded into q
    int c = (o8 % 192) >> 3;
    int rest = o8 / 192;
    int s = rest & 2047, h = rest >> 11;
    const u16* qrow = q + ((size_t)s * 32 + h) * 192;
    s16x8 out;
    if (c < 16) {
      s16x8 v = *reinterpret_cast<const s16x8*>(qrow + c * 8);
#pragma unroll
      for (int j = 0; j < 8; ++j) out[j] = (short)f2bf(bf2f((u16)v[j]) * scale);
    } else {
      int j0 = c * 8 - 128;
      bool lo = j0 < 32;
      int jj0 = lo ? j0 : j0 - 32;
      s16x8 a = *reinterpret_cast<const s16x8*>(qrow + 128 + 2 * jj0);
      s16x8 b = *reinterpret_cast<const s16x8*>(qrow + 128 + 2 * jj0 + 8);
      float4 c0 = *reinterpret_cast<const float4*>(cost + s * 32 + jj0);
      float4 c1 = *reinterpret_cast<const float4*>(cost + s * 32 + jj0 + 4);
      float4 s0 = *reinterpret_cast<const float4*>(sint + s * 32 + jj0);
      float4 s1 = *reinterpret_cast<const float4*>(sint + s * 32 + jj0 + 4);
      float cs[8] = {c0.x, c0.y, c0.z, c0.w, c1.x, c1.y, c1.z, c1.w};
      float sn[8] = {s0.x, s0.y, s0.z, s0.w, s1.x, s1.y, s1.z, s1.w};
#pragma unroll
      for (int j = 0; j < 8; ++j) {
        float x0 = bf2f((u16)((j < 4) ? a[2 * j] : b[2 * j - 8]));
        float x1 = bf2f((u16)((j < 4) ? a[2 * j + 1] : b[2 * j - 7]));
        float v = lo ? (x0 * cs[j] - x1 * sn[j]) : (x1 * cs[j] + x0 * sn[j]);
        out[j] = (short)f2bf(v * scale);
      }
    }
    *reinterpret_cast<s16x8*>(qf + o8) = out;
  } else {
    int o8 = ((bid - 6144) * 256 + t) * 8;   // 32*2048*64 range
    int j0 = o8 & 63;
    int rest = o8 >> 6;
    int s = rest & 2047, h = rest >> 11;
    bool lo = j0 < 32;
    int jj0 = lo ? j0 : j0 - 32;
    const u16* crow = ckv + (size_t)s * 2112 + 512;
    s16x8 a = *reinterpret_cast<const s16x8*>(crow + 2 * jj0);
    s16x8 b = *reinterpret_cast<const s16x8*>(crow + 2 * jj0 + 8);
    float4 c0 = *reinterpret_cast<const float4*>(cost + s * 32 + jj0);
    float4 c1 = *reinterpret_cast<const float4*>(cost + s * 32 + jj0 + 4);
    float4 s0 = *reinterpret_cast<const float4*>(sint + s * 32 + jj0);
    float4 s1 = *reinterpret_cast<const float4*>(sint + s * 32 + jj0 + 4);
    float cs[8] = {c0.x, c0.y, c0.z, c0.w, c1.x, c1.y, c1.z, c1.w};
    float sn[8] = {s0.x, s0.y, s0.z, s0.w, s1.x, s1.y, s1.z, s1.w};
    s16x8 out;
#pragma unroll
    for (int j = 0; j < 8; ++j) {
      float x0 = bf2f((u16)((j < 4) ? a[2 * j] : b[2 * j - 8]));
      float x1 = bf2f((u16)((j < 4) ? a[2 * j + 1] : b[2 * j - 7]));
      float v = lo ? (x0 * cs[j] - x1 * sn[j]) : (x1 * cs[j] + x0 * sn[j]);
      out[j] = (short)f2bf(v);
    }
    *reinterpret_cast<s16x8*>(kf + ((size_t)h * 2048 + s) * 192 + 128 + j0) = out;
  }
}

// ---------------- GEMM v3 body (128x128, for ragged fused1) ----------------
template <int EPI>
__device__ __forceinline__ void gemm_v3_body(const u16* __restrict__ A,
                                             const u16* __restrict__ BT,
                                             void* __restrict__ Cv,
                                             void* __restrict__ Cv2,
                                             int M, int N, int K,
                                             int bx, int by, u16* S) {
  const int t0 = threadIdx.x;
  const int lane = t0 & 63, wave = t0 >> 6;
  const int wr = wave >> 1, wc = wave & 1;
  const int row0 = by * 128, col0 = bx * 128;
  const int lrow = lane & 15, lkg = lane >> 4;

  const int lp = lane ^ ((lane >> 3) & 3);
  const int srow_off = lp >> 2;
  const int skel = (lp & 3) * 8;
  const int c0 = wave * 2, c1 = c0 + 1;
  const int arow_c0 = row0 + c0 * 16 + srow_off;
  const int arow_c1 = row0 + c1 * 16 + srow_off;
  int brow_c0 = col0 + c0 * 16 + srow_off; if (brow_c0 > N - 1) brow_c0 = N - 1;
  int brow_c1 = col0 + c1 * 16 + srow_off; if (brow_c1 > N - 1) brow_c1 = N - 1;

  int aoff[4], boff[4];
#pragma unroll
  for (int m = 0; m < 4; ++m) {
    int r = wr * 64 + m * 16 + lrow;
    int off = r * 32 + lkg * 8;
    aoff[m] = off ^ ((off >> 3) & 0x18);
    r = wc * 64 + m * 16 + lrow;
    off = r * 32 + lkg * 8;
    boff[m] = off ^ ((off >> 3) & 0x18);
  }

  const int NT = K >> 5;

#pragma unroll
  for (int pt = 0; pt < 3; ++pt) {
    u16* ab = &S[pt * 8192];
    const int kb = pt * 32 + skel;
    gload16(A  + (size_t)arow_c0 * K + kb, ab + c0 * 512);
    gload16(A  + (size_t)arow_c1 * K + kb, ab + c1 * 512);
    gload16(BT + (size_t)brow_c0 * K + kb, ab + 4096 + c0 * 512);
    gload16(BT + (size_t)brow_c1 * K + kb, ab + 4096 + c1 * 512);
  }

  f32x4 acc[4][4];
#pragma unroll
  for (int m = 0; m < 4; ++m)
#pragma unroll
    for (int n = 0; n < 4; ++n) acc[m][n] = 0.f;

  for (int t = 0; t < NT; ++t) {
    if (t + 2 < NT)      asm volatile("s_waitcnt vmcnt(8)" ::: "memory");
    else if (t + 1 < NT) asm volatile("s_waitcnt vmcnt(4)" ::: "memory");
    else                 asm volatile("s_waitcnt vmcnt(0)" ::: "memory");
    __builtin_amdgcn_s_barrier();
    __builtin_amdgcn_sched_barrier(0);

    const u16* ab = &S[(t & 3) * 8192];
    bf16x8 af[4], bb[4];
#pragma unroll
    for (int m = 0; m < 4; ++m)
      af[m] = *reinterpret_cast<const bf16x8*>(ab + aoff[m]);
#pragma unroll
    for (int n = 0; n < 4; ++n)
      bb[n] = *reinterpret_cast<const bf16x8*>(ab + 4096 + boff[n]);

    if (t + 3 < NT) {
      u16* sb = &S[((t + 3) & 3) * 8192];
      const int kb = (t + 3) * 32 + skel;
      gload16(A  + (size_t)arow_c0 * K + kb, sb + c0 * 512);
      gload16(A  + (size_t)arow_c1 * K + kb, sb + c1 * 512);
      gload16(BT + (size_t)brow_c0 * K + kb, sb + 4096 + c0 * 512);
      gload16(BT + (size_t)brow_c1 * K + kb, sb + 4096 + c1 * 512);
    }

    __builtin_amdgcn_s_setprio(1);
#pragma unroll
    for (int m = 0; m < 4; ++m)
#pragma unroll
      for (int n = 0; n < 4; ++n)
        acc[m][n] = __builtin_amdgcn_mfma_f32_16x16x32_bf16(af[m], bb[n], acc[m][n], 0, 0, 0);
    __builtin_amdgcn_s_setprio(0);
  }

#pragma unroll
  for (int m = 0; m < 4; ++m) {
#pragma unroll
    for (int n = 0; n < 4; ++n) {
      int col = col0 + wc * 64 + n * 16 + lrow;
      int row = row0 + wr * 64 + m * 16 + lkg * 4;
      if (col < N) {
#pragma unroll
        for (int i = 0; i < 4; ++i) {
          size_t idx = (size_t)(row + i) * N + col;
          if (EPI == 1) ((u16*)Cv)[idx] = f2bf(acc[m][n][i]);
          else          ((float*)Cv)[idx] = acc[m][n][i];
        }
      }
    }
  }
}

template <int EPI>
__global__ __launch_bounds__(256) void gemm_v3_kernel(const u16* __restrict__ A,
                                                      const u16* __restrict__ BT,
                                                      void* __restrict__ Cv,
                                                      void* __restrict__ Cv2,
                                                      int M, int N, int K) {
  __shared__ __align__(16) u16 S[4 * 8192];
  gemm_v3_body<EPI>(A, BT, Cv, Cv2, M, N, K, blockIdx.x, blockIdx.y, S);
}

// ---------------- GEMM v4 body: 128(M)x256(N) tile, per-wave 64x128 ----------------
template <int EPI>
__device__ __forceinline__ void gemm_v4_body(const u16* __restrict__ A,
                                             const u16* __restrict__ BT,
                                             void* __restrict__ Cv,
                                             void* __restrict__ Cv2,
                                             int M, int N, int K,
                                             int bx, int by, u16* S) {
  const int t0 = threadIdx.x;
  const int lane = t0 & 63, wave = t0 >> 6;
  const int wr = wave >> 1, wc = wave & 1;
  const int row0 = by * 128, col0 = bx * 256;
  const int lrow = lane & 15, lkg = lane >> 4;

  const int lp = lane ^ ((lane >> 3) & 3);
  const int srow_off = lp >> 2;
  const int skel = (lp & 3) * 8;

  const int ac0 = wave * 2, ac1 = ac0 + 1;
  const int arow_0 = row0 + ac0 * 16 + srow_off;
  const int arow_1 = row0 + ac1 * 16 + srow_off;
  int brow[4];
#pragma unroll
  for (int j = 0; j < 4; ++j) {
    int r = col0 + (wave * 4 + j) * 16 + srow_off;
    brow[j] = (r > N - 1) ? (N - 1) : r;
  }

  int aoff[4], boff[8];
#pragma unroll
  for (int m = 0; m < 4; ++m) {
    int r = wr * 64 + m * 16 + lrow;
    int off = r * 32 + lkg * 8;
    aoff[m] = off ^ ((off >> 3) & 0x18);
  }
#pragma unroll
  for (int n = 0; n < 8; ++n) {
    int r = wc * 128 + n * 16 + lrow;
    int off = r * 32 + lkg * 8;
    boff[n] = off ^ ((off >> 3) & 0x18);
  }

  const int NT = K >> 5;

#pragma unroll
  for (int pt = 0; pt < 2; ++pt) {
    u16* sb = &S[pt * 12288];
    const int kb = pt * 32 + skel;
    gload16(A + (size_t)arow_0 * K + kb, sb + ac0 * 512);
    gload16(A + (size_t)arow_1 * K + kb, sb + ac1 * 512);
#pragma unroll
    for (int j = 0; j < 4; ++j)
      gload16(BT + (size_t)brow[j] * K + kb, sb + 4096 + (wave * 4 + j) * 512);
  }

  f32x4 acc[4][8];
#pragma unroll
  for (int m = 0; m < 4; ++m)
#pragma unroll
    for (int n = 0; n < 8; ++n) acc[m][n] = 0.f;

  int bufr = 0, bufw = 2;
  for (int t = 0; t < NT; ++t) {
    if (t + 2 < NT) {
      u16* sb = &S[bufw * 12288];
      const int kb = (t + 2) * 32 + skel;
      gload16(A + (size_t)arow_0 * K + kb, sb + ac0 * 512);
      gload16(A + (size_t)arow_1 * K + kb, sb + ac1 * 512);
#pragma unroll
      for (int j = 0; j < 4; ++j)
        gload16(BT + (size_t)brow[j] * K + kb, sb + 4096 + (wave * 4 + j) * 512);
      bufw = (bufw + 1 == 3) ? 0 : bufw + 1;
      asm volatile("s_waitcnt vmcnt(12)" ::: "memory");
    } else if (t + 1 < NT) {
      asm volatile("s_waitcnt vmcnt(6)" ::: "memory");
    } else {
      asm volatile("s_waitcnt vmcnt(0)" ::: "memory");
    }
    __builtin_amdgcn_s_barrier();
    __builtin_amdgcn_sched_barrier(0);

    const u16* ab = &S[bufr * 12288];
    bufr = (bufr + 1 == 3) ? 0 : bufr + 1;
    bf16x8 af[4];
#pragma unroll
    for (int m = 0; m < 4; ++m)
      af[m] = *reinterpret_cast<const bf16x8*>(ab + aoff[m]);

    __builtin_amdgcn_s_setprio(1);
#pragma unroll
    for (int n = 0; n < 8; ++n) {
      bf16x8 bbn = *reinterpret_cast<const bf16x8*>(ab + 4096 + boff[n]);
#pragma unroll
      for (int m = 0; m < 4; ++m)
        acc[m][n] = __builtin_amdgcn_mfma_f32_16x16x32_bf16(af[m], bbn, acc[m][n], 0, 0, 0);
    }
    __builtin_amdgcn_s_setprio(0);
  }

#pragma unroll
  for (int m = 0; m < 4; ++m) {
#pragma unroll
    for (int n = 0; n < 8; ++n) {
      int col = col0 + wc * 128 + n * 16 + lrow;
      int row = row0 + wr * 64 + m * 16 + lkg * 4;
      if (EPI == 2) {
        int d = col & 255, hh = col >> 8;
        if (d < 128) {
          u16* dst = (u16*)Cv + ((size_t)hh * 2048 + row) * 192 + d;
#pragma unroll
          for (int i = 0; i < 4; ++i) dst[(size_t)i * 192] = f2bf(acc[m][n][i]);
        } else {
          s16x4 v;
#pragma unroll
          for (int i = 0; i < 4; ++i) v[i] = (short)f2bf(acc[m][n][i]);
          *reinterpret_cast<s16x4*>((u16*)Cv2 + ((size_t)hh * 128 + (d - 128)) * 2048 + row) = v;
        }
      } else if (col < N) {
#pragma unroll
        for (int i = 0; i < 4; ++i) {
          size_t idx = (size_t)(row + i) * N + col;
          if (EPI == 1) ((u16*)Cv)[idx] = f2bf(acc[m][n][i]);
          else          ((float*)Cv)[idx] = acc[m][n][i];
        }
      }
    }
  }
}

template <int EPI>
__global__ __launch_bounds__(256, 2) void gemm_v4_kernel(const u16* __restrict__ A,
                                                         const u16* __restrict__ BT,
                                                         void* __restrict__ Cv,
                                                         void* __restrict__ Cv2,
                                                         int M, int N, int K) {
  __shared__ __align__(16) u16 S[3 * 12288];
  gemm_v4_body<EPI>(A, BT, Cv, Cv2, M, N, K, blockIdx.x, blockIdx.y, S);
}

__global__ __launch_bounds__(256, 2) void gemm_qkv_kernel(const u16* __restrict__ qan,
                                                          const u16* __restrict__ WqbT,
                                                          u16* __restrict__ qout,
                                                          const u16* __restrict__ cn,
                                                          const u16* __restrict__ WkvbT,
                                                          u16* __restrict__ kfb,
                                                          u16* __restrict__ vTb) {
  __shared__ __align__(16) u16 S[3 * 12288];
  if (blockIdx.z == 0) {
    if (blockIdx.x >= 24) return;
    gemm_v4_body<1>(qan, WqbT, qout, nullptr, 2048, 6144, 1536, blockIdx.x, blockIdx.y, S);
  } else {
    gemm_v4_body<2>(cn, WkvbT, kfb, vTb, 2048, 8192, 512, blockIdx.x, blockIdx.y, S);
  }
}

// ---------------- causal flash attention v7: KVBLK=64, K dbuf + counted vmcnt, V post-PV ----------------
// grid (h=32, pair=16): bid%8 = h%8 head-pinned XCD. 512 blocks = 2/CU
// (LDS 73KB: Kt 2x24K dbuf + Vt 16K single + Pl 9K). Block handles qb=pair and
// 31-pair (33 KV-64 iters). 4 waves x 16 rows. Per iter, per wave:
//   issue K(t+1) 6 chunks -> vmcnt(6) [retires K(t)+V(t); K(t+1) stays in flight]
//   -> barrier -> QK/softmax/PV -> barrier -> issue V(t+1) 4 chunks into Vt.
// Issue order K(t+1),V(t+1),K(t+2) makes vmcnt(6) at iter t+1 retire exactly
// K(t+1)+V(t+1). V writes into Vt only after the post-PV barrier (all PV reads
// done). Halves softmax/mask/barrier count vs KVBLK=32 while keeping prefetch
// in flight (r14 showed stall removal; r9 showed low VALU -- this combines them).
__global__ __launch_bounds__(256) void mla_attn_kernel(const u16* __restrict__ qf,
                                                       const u16* __restrict__ kf,
                                                       const u16* __restrict__ vT,
                                                       u16* __restrict__ o) {
  const int h = blockIdx.x, pair = blockIdx.y;
  const int t = threadIdx.x, wave = t >> 6, lane = t & 63;
  const int lrow = lane & 15, lkg = lane >> 4;
  __shared__ __align__(16) u16 Kt[2][24 * 512];   // (cg,kk): K[cg*16+l&15][kk*32+(l>>4)*8]
  __shared__ __align__(16) u16 Vt[16 * 512];      // (f,ck):  vT[f*16+l&15][ck*32+(l>>4)*8]
  __shared__ __align__(16) u16 Pl[4][16][72];

  // per-lane staging sources (wave w stages K rows cg=w, V d-rows f=2w,2w+1)
  const u16* ksrc0 = kf + ((size_t)h * 2048 + wave * 16 + lrow) * 192 + lkg * 8;
  const u16* vsrc0 = vT + ((size_t)h * 128 + wave * 32 + lrow) * 2048 + lkg * 8;

  for (int qq = 0; qq < 2; ++qq) {
    const int qb = qq ? (31 - pair) : pair;
    const int qbase = qb * 64 + wave * 16;

    bf16x8 qfr[6];
    const u16* qrow_ptr = qf + ((size_t)h * 2048 + qbase + lrow) * 192;
#pragma unroll
    for (int kk = 0; kk < 6; ++kk)
      qfr[kk] = *reinterpret_cast<const bf16x8*>(qrow_ptr + kk * 32 + lkg * 8);

    f32x4 acc_o[8];
#pragma unroll
    for (int f = 0; f < 8; ++f) acc_o[f] = 0.f;
    float m_run[4], l_par[4];
#pragma unroll
    for (int i = 0; i < 4; ++i) { m_run[i] = -1e30f; l_par[i] = 0.f; }

    const int nt = qb + 1;   // KV tiles of 64

    // prologue: K(0) -> Kt[0], V(0) -> Vt
#pragma unroll
    for (int kk = 0; kk < 6; ++kk)
      gload16(ksrc0 + kk * 32, &Kt[0][(wave * 6 + kk) * 512]);
#pragma unroll
    for (int j = 0; j < 4; ++j) {
      int fo = (j >> 1), ck = j & 1;
      gload16(vsrc0 + (size_t)fo * 16 * 2048 + ck * 32,
              &Vt[((wave * 2 + fo) * 2 + ck) * 512]);
    }

    for (int it = 0; it < nt; ++it) {
      const int kt = it * 64;
      if (it + 1 < nt) {   // prefetch K(t+1) into other K buffer
        const u16* ks = ksrc0 + (size_t)(kt + 64) * 192;
        u16* kd = &Kt[(it + 1) & 1][0];
#pragma unroll
        for (int kk = 0; kk < 6; ++kk)
          gload16(ks + kk * 32, kd + (wave * 6 + kk) * 512);
        asm volatile("s_waitcnt vmcnt(6)" ::: "memory");  // K(t)+V(t) retired; K(t+1) in flight
      } else {
        asm volatile("s_waitcnt vmcnt(0)" ::: "memory");
      }
      __builtin_amdgcn_s_barrier();
      __builtin_amdgcn_sched_barrier(0);

      const u16* Kb = &Kt[it & 1][0];
      // ---- S = Q K^T (16 x 64) from LDS ----
      f32x4 sv[4];
#pragma unroll
      for (int cg = 0; cg < 4; ++cg) sv[cg] = 0.f;
#pragma unroll
      for (int cg = 0; cg < 4; ++cg)
#pragma unroll
        for (int kk = 0; kk < 6; ++kk) {
          bf16x8 kfr = *reinterpret_cast<const bf16x8*>(&Kb[(cg * 6 + kk) * 512 + lane * 8]);
          sv[cg] = __builtin_amdgcn_mfma_f32_16x16x32_bf16(qfr[kk], kfr, sv[cg], 0, 0, 0);
        }

      const int qrow_b = qbase + lkg * 4;
      if (it + 1 == nt) {   // diagonal tile
#pragma unroll
        for (int cg = 0; cg < 4; ++cg) {
          int kvcol = kt + cg * 16 + lrow;
#pragma unroll
          for (int i = 0; i < 4; ++i)
            if (kvcol > qrow_b + i) sv[cg][i] = -__builtin_inff();
        }
      }
      // ---- softmax: defer-max + deferred-l ----
      float tmax[4];
#pragma unroll
      for (int i = 0; i < 4; ++i)
        tmax[i] = fmaxf(fmaxf(sv[0][i], sv[1][i]), fmaxf(sv[2][i], sv[3][i]));
#pragma unroll
      for (int m = 8; m >= 1; m >>= 1)
#pragma unroll
        for (int i = 0; i < 4; ++i) tmax[i] = fmaxf(tmax[i], __shfl_xor(tmax[i], m));
      int need = 0;
#pragma unroll
      for (int i = 0; i < 4; ++i) need |= (tmax[i] > m_run[i] + 8.f) ? 1 : 0;
      if (__any(need)) {
#pragma unroll
        for (int i = 0; i < 4; ++i) {
          float mnew = fmaxf(m_run[i], tmax[i]);
          float alpha = __expf(m_run[i] - mnew);
          m_run[i] = mnew;
          l_par[i] *= alpha;
#pragma unroll
          for (int f = 0; f < 8; ++f) acc_o[f][i] *= alpha;
        }
      }
#pragma unroll
      for (int i = 0; i < 4; ++i) {
#pragma unroll
        for (int cg = 0; cg < 4; ++cg) sv[cg][i] = __expf(sv[cg][i] - m_run[i]);
        l_par[i] += (sv[0][i] + sv[1][i]) + (sv[2][i] + sv[3][i]);
      }
      // ---- P -> bf16 -> per-wave LDS ----
#pragma unroll
      for (int cg = 0; cg < 4; ++cg)
#pragma unroll
        for (int i = 0; i < 4; ++i)
          Pl[wave][lkg * 4 + i][cg * 16 + lrow] = f2bf(sv[cg][i]);
      // ---- O += P V (V from single-buffer LDS) ----
#pragma unroll
      for (int ck = 0; ck < 2; ++ck) {
        bf16x8 pf = *reinterpret_cast<const bf16x8*>(&Pl[wave][lrow][ck * 32 + lkg * 8]);
#pragma unroll
        for (int f = 0; f < 8; ++f) {
          bf16x8 vfr = *reinterpret_cast<const bf16x8*>(&Vt[(f * 2 + ck) * 512 + lane * 8]);
          acc_o[f] = __builtin_amdgcn_mfma_f32_16x16x32_bf16(pf, vfr, acc_o[f], 0, 0, 0);
        }
      }
      __builtin_amdgcn_sched_barrier(0);
      __builtin_amdgcn_s_barrier();   // all waves done reading Vt (and Kt[it&1])
      if (it + 1 < nt) {              // stage V(t+1) into Vt (post-barrier: safe)
        const u16* vs = vsrc0 + kt + 64;
#pragma unroll
        for (int j = 0; j < 4; ++j) {
          int fo = (j >> 1), ck = j & 1;
          gload16(vs + (size_t)fo * 16 * 2048 + ck * 32,
                  &Vt[((wave * 2 + fo) * 2 + ck) * 512]);
        }
      }
    }
    // ---- epilogue: one l reduce, divide, store ----
#pragma unroll
    for (int i = 0; i < 4; ++i)
#pragma unroll
      for (int m = 8; m >= 1; m >>= 1) l_par[i] += __shfl_xor(l_par[i], m);
#pragma unroll
    for (int f = 0; f < 8; ++f)
#pragma unroll
      for (int i = 0; i < 4; ++i) {
        int row = qbase + lkg * 4 + i;
        int col = h * 128 + f * 16 + lrow;
        o[(size_t)row * 4096 + col] = f2bf(acc_o[f][i] / l_par[i]);
      }
  }
}

// ---------------------------------------------------------------
extern "C" void kernel_launch(void* const* d_in, const int* in_sizes, int n_in,
                              void* d_out, int out_size, void* d_ws, size_t ws_size,
                              hipStream_t stream) {
  (void)in_sizes; (void)n_in; (void)out_size; (void)ws_size;
  const float* hs   = (const float*)d_in[0];
  const float* Wqa  = (const float*)d_in[1];
  const float* qln  = (const float*)d_in[2];
  const float* Wqb  = (const float*)d_in[3];
  const float* Wkva = (const float*)d_in[4];
  const float* kvln = (const float*)d_in[5];
  const float* Wkvb = (const float*)d_in[6];
  const float* Wo   = (const float*)d_in[7];
  float* out = (float*)d_out;

  char* p = (char*)d_ws;
  size_t off = 0;
  auto carve = [&](size_t bytes) {
    char* r = p + off;
    off += (bytes + 255) & ~(size_t)255;
    return r;
  };
  u16* hs_bf = (u16*)carve((size_t)2048 * 4096 * 2);
  u16* WabT  = (u16*)carve((size_t)2112 * 4096 * 2);   // [0..1535]=WqaT, [1536..2111]=WkvaT
  u16* WqbT  = (u16*)carve((size_t)6144 * 1536 * 2);
  u16* WkvbT = (u16*)carve((size_t)8192 * 512 * 2);
  u16* WoT   = (u16*)carve((size_t)4096 * 4096 * 2);
  u16* fused = (u16*)carve((size_t)2048 * 2112 * 2);   // [qa | ckv] per row
  u16* qan   = (u16*)carve((size_t)2048 * 1536 * 2);
  u16* q     = (u16*)carve((size_t)2048 * 6144 * 2);
  u16* cn    = (u16*)carve((size_t)2048 * 512 * 2);
  u16* qfb   = (u16*)carve((size_t)32 * 2048 * 192 * 2);
  u16* kfb   = (u16*)carve((size_t)32 * 2048 * 192 * 2);
  u16* vTb   = (u16*)carve((size_t)32 * 128 * 2048 * 2);
  u16* ob    = (u16*)carve((size_t)2048 * 4096 * 2);
  float* cost = (float*)carve((size_t)65536 * 4);
  float* sint = (float*)carve((size_t)65536 * 4);

  // --- merged prep: cast + 5 transposes + rope table (1 launch) ---
  prep_merged_kernel<<<17984, 256, 0, stream>>>(hs, hs_bf, Wqa, Wkva, WabT,
                                                Wqb, WqbT, Wkvb, WkvbT, Wo, WoT,
                                                cost, sint);

  // --- fused first-stage GEMM (ragged N=2112 -> v3) ---
  gemm_v3_kernel<1><<<dim3(17, 16), 256, 0, stream>>>(hs_bf, WabT, fused, nullptr, 2048, 2112, 4096);

  // --- merged norms (1 launch) ---
  norms_merged_kernel<<<4096, 256, 0, stream>>>(fused, qln, kvln, qan, cn);

  // --- merged q+kv second-stage GEMMs (v4 tiles; exact-fit N) ---
  gemm_qkv_kernel<<<dim3(32, 16, 2), 256, 0, stream>>>(qan, WqbT, q, cn, WkvbT, kfb, vTb);

  // --- merged builds: qf RoPE+scale, kf RoPE (1 launch) ---
  builds_merged_kernel<<<8192, 256, 0, stream>>>(q, fused + 1536, cost, sint, qfb, kfb);

  // --- attention v7 (512 blocks, 2/CU, KVBLK=64, K dbuf + counted vmcnt) ---
  mla_attn_kernel<<<dim3(32, 16), 256, 0, stream>>>(qfb, kfb, vTb, ob);

  // --- output projection (v4: 16x16 = 256 blocks, exact 1/CU) ---
  gemm_v4_kernel<0><<<dim3(16, 16), 256, 0, stream>>>(ob, WoT, out, nullptr, 2048, 4096, 4096);
}